// Round 1
// baseline (361.132 us; speedup 1.0000x reference)
//
#include <hip/hip_runtime.h>

// Problem constants: N=256, T=12, F=32, T_dim=8, D=64
// q/k/v layout: [b=(n*8+kk)][t][d] flat: ((n*8+kk)*12+t)*64+d, total 2048*768 floats

#define QK_SZ 1572864   // 2048*12*64

// ---------------------------------------------------------------- K0: transpose w3/w4
__global__ __launch_bounds__(256) void transpose_w_kernel(
    const float* __restrict__ w3, const float* __restrict__ w4,
    float* __restrict__ w3t, float* __restrict__ w4t)
{
    int e = blockIdx.x * 256 + threadIdx.x;   // grid 128 -> 32768
    {   // w3: (64 dout, 512 c) -> w3t[c*64+dout]
        int dout = e >> 9, c = e & 511;
        w3t[c * 64 + dout] = w3[e];
    }
    if (e < 2048) {  // w4: (32 f, 64 d) -> w4t[d*32+f]
        int f = e >> 6, d = e & 63;
        w4t[d * 32 + f] = w4[e];
    }
}

// ---------------------------------------------------------------- K1: QKV projection
__global__ __launch_bounds__(256) void qkv_kernel(
    const float* __restrict__ x,
    const float* __restrict__ Wq, const float* __restrict__ Wk, const float* __restrict__ Wv,
    const float* __restrict__ bq, const float* __restrict__ bk, const float* __restrict__ bv,
    float* __restrict__ q, float* __restrict__ k, float* __restrict__ v)
{
    int b = blockIdx.x;          // 0..2047
    int n = b >> 3;
    __shared__ float xs[384];    // x[n]: 12x32
    int tid = threadIdx.x;
    if (tid < 96) ((float4*)xs)[tid] = ((const float4*)(x + n * 384))[tid];
    __syncthreads();

    int d = tid & 63, tg = tid >> 6;   // d 0..63, tg 0..3 (t = tg + 4*tt)
    const float* wqb = Wq + (size_t)b * 2048 + d;
    const float* wkb = Wk + (size_t)b * 2048 + d;
    const float* wvb = Wv + (size_t)b * 2048 + d;
    float aq[3] = {0.f,0.f,0.f}, ak[3] = {0.f,0.f,0.f}, av[3] = {0.f,0.f,0.f};
    #pragma unroll 8
    for (int f = 0; f < 32; ++f) {
        float wq = wqb[f * 64], wk = wkb[f * 64], wv = wvb[f * 64];
        #pragma unroll
        for (int tt = 0; tt < 3; ++tt) {
            float xv = xs[(tg + tt * 4) * 32 + f];
            aq[tt] += xv * wq; ak[tt] += xv * wk; av[tt] += xv * wv;
        }
    }
    float bqv = bq[b * 64 + d], bkv = bk[b * 64 + d], bvv = bv[b * 64 + d];
    #pragma unroll
    for (int tt = 0; tt < 3; ++tt) {
        int t = tg + tt * 4;
        size_t o = ((size_t)b * 12 + t) * 64 + d;
        q[o] = aq[tt] + bqv;
        k[o] = ak[tt] + bkv;
        v[o] = av[tt] + bvv;
    }
}

// ---------------------------------------------------------------- K2: pairwise scores s[i,j]
// block: 16 i x 8 j pairs x 2 d-halves = 256 threads; grid dim3(32, 16)
// s[i,j] = b2 + sum_m w2[m]*relu(0.125*sum_{kk,t,ss}(q_i . k_j)*w1[m,kk,t,ss] + b1[m])
__global__ __launch_bounds__(256, 2) void score_kernel(
    const float* __restrict__ qg, const float* __restrict__ kg,
    const float* __restrict__ w1, const float* __restrict__ b1g,
    const float* __restrict__ w2g, const float* __restrict__ b2g,
    float* __restrict__ sout)
{
    __shared__ float ks[8 * 772];    // 8 j-rows of 768, padded to 772 (bank spread)
    __shared__ float w1t[1152];      // [z=t*12+ss][m] for current kk
    __shared__ float red[128 * 8];   // dh-reduction buffer

    int tid = threadIdx.x;
    int pairid = tid & 127, dh = tid >> 7;
    int ii = pairid >> 3, jj = pairid & 7;
    int ib = blockIdx.y * 16, jb = blockIdx.x * 8;
    int d0 = dh * 32;

    float hacc[8] = {0.f,0.f,0.f,0.f,0.f,0.f,0.f,0.f};

    for (int kk = 0; kk < 8; ++kk) {
        __syncthreads();
        // stage K tile: 8 rows x 768 floats = 1536 float4 / 256 threads
        #pragma unroll
        for (int r = 0; r < 6; ++r) {
            int e = tid + r * 256;           // 0..1535
            int js = e / 192, rem = e % 192;
            float4 val = *(const float4*)(kg + ((size_t)((jb + js) * 8 + kk)) * 768 + rem * 4);
            *(float4*)(ks + js * 772 + rem * 4) = val;
        }
        // stage w1 slab transposed: w1t[z*8+m] = w1[m*1152 + kk*144 + z]
        for (int e = tid; e < 1152; e += 256)
            w1t[e] = w1[(e & 7) * 1152 + kk * 144 + (e >> 3)];
        __syncthreads();

        const float* qrow = qg + ((size_t)((ib + ii) * 8 + kk)) * 768 + d0;
        for (int tb = 0; tb < 12; tb += 4) {
            float qr[4][32];
            #pragma unroll
            for (int tt = 0; tt < 4; ++tt) {
                const float4* qp = (const float4*)(qrow + (tb + tt) * 64);
                #pragma unroll
                for (int w = 0; w < 8; ++w) {
                    float4 t4 = qp[w];
                    qr[tt][w*4+0] = t4.x; qr[tt][w*4+1] = t4.y;
                    qr[tt][w*4+2] = t4.z; qr[tt][w*4+3] = t4.w;
                }
            }
            for (int s = 0; s < 12; ++s) {
                const float4* kp = (const float4*)(ks + jj * 772 + s * 64 + d0);
                float dt[4] = {0.f,0.f,0.f,0.f};
                #pragma unroll
                for (int w = 0; w < 8; ++w) {
                    float4 kv = kp[w];
                    #pragma unroll
                    for (int tt = 0; tt < 4; ++tt) {
                        dt[tt] += qr[tt][w*4+0]*kv.x + qr[tt][w*4+1]*kv.y
                                + qr[tt][w*4+2]*kv.z + qr[tt][w*4+3]*kv.w;
                    }
                }
                #pragma unroll
                for (int tt = 0; tt < 4; ++tt) {
                    int z = (tb + tt) * 12 + s;
                    const float4* wp = (const float4*)(w1t + z * 8);
                    float4 wa = wp[0], wb = wp[1];
                    hacc[0] += dt[tt]*wa.x; hacc[1] += dt[tt]*wa.y;
                    hacc[2] += dt[tt]*wa.z; hacc[3] += dt[tt]*wa.w;
                    hacc[4] += dt[tt]*wb.x; hacc[5] += dt[tt]*wb.y;
                    hacc[6] += dt[tt]*wb.z; hacc[7] += dt[tt]*wb.w;
                }
            }
        }
    }

    __syncthreads();
    if (dh == 1) {
        #pragma unroll
        for (int m = 0; m < 8; ++m) red[pairid * 8 + m] = hacc[m];
    }
    __syncthreads();
    if (dh == 0) {
        float sv = b2g[0];
        #pragma unroll
        for (int m = 0; m < 8; ++m) {
            float hm = 0.125f * (hacc[m] + red[pairid * 8 + m]) + b1g[m];
            sv += fmaxf(hm, 0.f) * w2g[m];
        }
        sout[(size_t)(ib + ii) * 256 + (jb + jj)] = sv;
    }
}

// ---------------------------------------------------------------- K3: row softmax
__global__ __launch_bounds__(256) void softmax_kernel(
    const float* __restrict__ s, float* __restrict__ att)
{
    int i = blockIdx.x, j = threadIdx.x;
    float v = s[(size_t)i * 256 + j];
    __shared__ float wred[4], wred2[4];

    float m = v;
    #pragma unroll
    for (int off = 32; off > 0; off >>= 1) m = fmaxf(m, __shfl_down(m, off, 64));
    if ((j & 63) == 0) wred[j >> 6] = m;
    __syncthreads();
    m = fmaxf(fmaxf(wred[0], wred[1]), fmaxf(wred[2], wred[3]));

    float e = expf(v - m);
    float sum = e;
    #pragma unroll
    for (int off = 32; off > 0; off >>= 1) sum += __shfl_down(sum, off, 64);
    if ((j & 63) == 0) wred2[j >> 6] = sum;
    __syncthreads();
    sum = wred2[0] + wred2[1] + wred2[2] + wred2[3];

    att[(size_t)i * 256 + j] = e / sum;
}

// ---------------------------------------------------------------- K4: b = att @ v (output layout [i][t][kk][d])
// grid dim3(24, 16): x = t*2+half, y = itile; 256 threads: kk = tid>>5, d = (tid&31)+half*32
__global__ __launch_bounds__(256) void av_kernel(
    const float* __restrict__ att, const float* __restrict__ vg, float* __restrict__ bmat)
{
    int t = blockIdx.x >> 1, half = blockIdx.x & 1, itile = blockIdx.y;
    int tid = threadIdx.x;
    __shared__ float atts[256 * 16];   // [j][iiq]
    #pragma unroll
    for (int r = 0; r < 16; ++r) {
        int e = tid + r * 256;
        int j = e >> 4, iiq = e & 15;
        atts[e] = att[(size_t)(itile * 16 + iiq) * 256 + j];
    }
    __syncthreads();

    int kk = tid >> 5;
    int d  = (tid & 31) + half * 32;
    float acc[16] = {0.f,0.f,0.f,0.f,0.f,0.f,0.f,0.f,0.f,0.f,0.f,0.f,0.f,0.f,0.f,0.f};
    const float* vp = vg + (size_t)kk * 768 + t * 64 + d;
    #pragma unroll 4
    for (int j = 0; j < 256; ++j) {
        float vv = vp[(size_t)j * 6144];
        const float4* ap = (const float4*)(atts + j * 16);
        #pragma unroll
        for (int g = 0; g < 4; ++g) {
            float4 a = ap[g];
            acc[g*4+0] += a.x * vv;
            acc[g*4+1] += a.y * vv;
            acc[g*4+2] += a.z * vv;
            acc[g*4+3] += a.w * vv;
        }
    }
    #pragma unroll
    for (int iiq = 0; iiq < 16; ++iiq)
        bmat[(((size_t)(itile * 16 + iiq) * 12 + t) * 8 + kk) * 64 + d] = acc[iiq];
}

// ---------------------------------------------------------------- K5: y = relu(b@w3T+b3)@w4T+b4
// 8 (i,t)-rows per block, 64 threads; grid 384
__global__ __launch_bounds__(64) void out_kernel(
    const float* __restrict__ bmat, const float* __restrict__ w3t, const float* __restrict__ b3,
    const float* __restrict__ w4t, const float* __restrict__ b4, float* __restrict__ yout)
{
    int rb = blockIdx.x * 8;
    int tid = threadIdx.x;
    __shared__ float rows[8 * 512];   // [r][kk*64+d]
    __shared__ float y1s[8 * 64];
    const float4* src = (const float4*)(bmat + (size_t)rb * 512);
    #pragma unroll
    for (int r = 0; r < 16; ++r) ((float4*)rows)[tid + r * 64] = src[tid + r * 64];
    __syncthreads();

    float acc[8];
    float b3v = b3[tid];
    #pragma unroll
    for (int r = 0; r < 8; ++r) acc[r] = b3v;
    for (int c = 0; c < 512; ++c) {             // c = d*8+kk (w3 column index)
        float wv = w3t[c * 64 + tid];
        int rowidx = ((c & 7) << 6) | (c >> 3); // -> kk*64+d
        #pragma unroll
        for (int r = 0; r < 8; ++r) acc[r] += rows[r * 512 + rowidx] * wv;
    }
    #pragma unroll
    for (int r = 0; r < 8; ++r) y1s[r * 64 + tid] = fmaxf(acc[r], 0.f);
    __syncthreads();

    int f = tid & 31, rg = tid >> 5;   // 2 row-groups x 4 rows
    #pragma unroll
    for (int rr = 0; rr < 4; ++rr) {
        int r = rg * 4 + rr;
        float a2 = b4[f];
        #pragma unroll
        for (int d = 0; d < 64; ++d) a2 += y1s[r * 64 + d] * w4t[d * 32 + f];
        yout[(size_t)(rb + r) * 32 + f] = a2;
    }
}

// ---------------------------------------------------------------- launch
extern "C" void kernel_launch(void* const* d_in, const int* in_sizes, int n_in,
                              void* d_out, int out_size, void* d_ws, size_t ws_size,
                              hipStream_t stream) {
    (void)in_sizes; (void)n_in; (void)out_size; (void)ws_size;
    const float* x  = (const float*)d_in[0];
    const float* Wq = (const float*)d_in[1];
    const float* Wk = (const float*)d_in[2];
    const float* Wv = (const float*)d_in[3];
    const float* bq = (const float*)d_in[4];
    const float* bk = (const float*)d_in[5];
    const float* bv = (const float*)d_in[6];
    const float* w1 = (const float*)d_in[7];
    const float* b1 = (const float*)d_in[8];
    const float* w2 = (const float*)d_in[9];
    const float* b2 = (const float*)d_in[10];
    const float* w3 = (const float*)d_in[11];
    const float* b3 = (const float*)d_in[12];
    const float* w4 = (const float*)d_in[13];
    const float* b4 = (const float*)d_in[14];

    float* ws   = (float*)d_ws;
    float* q    = ws;                  // 1572864
    float* k    = ws + (size_t)QK_SZ;      // 1572864
    float* v    = ws + (size_t)2 * QK_SZ;  // 1572864
    float* s    = ws + (size_t)3 * QK_SZ;  // 65536
    float* bmat = s + 65536;               // 1572864
    float* w3t  = bmat + QK_SZ;            // 32768
    float* w4t  = w3t + 32768;             // 2048

    float* yout = (float*)d_out;              // 98304
    float* att  = (float*)d_out + 98304;      // 65536

    transpose_w_kernel<<<128, 256, 0, stream>>>(w3, w4, w3t, w4t);
    qkv_kernel<<<2048, 256, 0, stream>>>(x, Wq, Wk, Wv, bq, bk, bv, q, k, v);
    score_kernel<<<dim3(32, 16), 256, 0, stream>>>(q, k, w1, b1, w2, b2, s);
    softmax_kernel<<<256, 256, 0, stream>>>(s, att);
    av_kernel<<<dim3(24, 16), 256, 0, stream>>>(att, v, bmat);
    out_kernel<<<384, 64, 0, stream>>>(bmat, w3t, b3, w4t, b4, yout);
}

// Round 2
// 158.941 us; speedup vs baseline: 2.2721x; 2.2721x over previous
//
#include <hip/hip_runtime.h>
#include <hip/hip_bf16.h>

// N=256, T=12, F=32, T_dim=8, D=64
// c-index (K of the big GEMM): c = kk*768 + t*64 + d, size 6144
typedef unsigned short ushort_t;
typedef __bf16 bf16x8 __attribute__((ext_vector_type(8)));
typedef float f32x4 __attribute__((ext_vector_type(4)));

#define GLOAD16(gp, lp) \
    __builtin_amdgcn_global_load_lds((const __attribute__((address_space(1))) void*)(gp), \
                                     (__attribute__((address_space(3))) void*)(lp), 16, 0, 0)

__device__ __forceinline__ ushort_t bf16bits(float x) {
    __hip_bfloat16 h = __float2bfloat16(x);
    return *(ushort_t*)&h;
}

// ---------------------------------------------------------------- K0: transpose w3/w4
__global__ __launch_bounds__(256) void transpose_w_kernel(
    const float* __restrict__ w3, const float* __restrict__ w4,
    float* __restrict__ w3t, float* __restrict__ w4t)
{
    int e = blockIdx.x * 256 + threadIdx.x;   // grid 128 -> 32768
    {   int dout = e >> 9, c = e & 511;
        w3t[c * 64 + dout] = w3[e]; }
    if (e < 2048) {
        int f = e >> 6, d = e & 63;
        w4t[d * 32 + f] = w4[e]; }
}

// ---------------------------------------------------------------- K1: QKV projection (+ Q split to bf16 hi/lo, scaled by 0.125)
__global__ __launch_bounds__(256) void qkv_kernel(
    const float* __restrict__ x,
    const float* __restrict__ Wq, const float* __restrict__ Wk, const float* __restrict__ Wv,
    const float* __restrict__ bq, const float* __restrict__ bk, const float* __restrict__ bv,
    ushort_t* __restrict__ qhi, ushort_t* __restrict__ qlo,
    float* __restrict__ k, float* __restrict__ v)
{
    int b = blockIdx.x;          // 0..2047
    int n = b >> 3;
    __shared__ float xs[384];
    int tid = threadIdx.x;
    if (tid < 96) ((float4*)xs)[tid] = ((const float4*)(x + n * 384))[tid];
    __syncthreads();

    int d = tid & 63, tg = tid >> 6;
    const float* wqb = Wq + (size_t)b * 2048 + d;
    const float* wkb = Wk + (size_t)b * 2048 + d;
    const float* wvb = Wv + (size_t)b * 2048 + d;
    float aq[3] = {0.f,0.f,0.f}, ak[3] = {0.f,0.f,0.f}, av[3] = {0.f,0.f,0.f};
    #pragma unroll 8
    for (int f = 0; f < 32; ++f) {
        float wq = wqb[f * 64], wk = wkb[f * 64], wv = wvb[f * 64];
        #pragma unroll
        for (int tt = 0; tt < 3; ++tt) {
            float xv = xs[(tg + tt * 4) * 32 + f];
            aq[tt] += xv * wq; ak[tt] += xv * wk; av[tt] += xv * wv;
        }
    }
    float bqv = bq[b * 64 + d], bkv = bk[b * 64 + d], bvv = bv[b * 64 + d];
    #pragma unroll
    for (int tt = 0; tt < 3; ++tt) {
        int t = tg + tt * 4;
        size_t o = ((size_t)b * 12 + t) * 64 + d;
        float qs = 0.125f * (aq[tt] + bqv);
        __hip_bfloat16 qh = __float2bfloat16(qs);
        float qhf = __bfloat162float(qh);
        qhi[o] = *(ushort_t*)&qh;
        qlo[o] = bf16bits(qs - qhf);
        k[o] = ak[tt] + bkv;
        v[o] = av[tt] + bvv;
    }
}

// ---------------------------------------------------------------- K2: G build
// G[(j*8+m)][kk*768+t*64+d] = sum_s w1[m][kk*144+t*12+s] * k[j*8+kk][s][d], split bf16 hi/lo
__global__ __launch_bounds__(256) void gbuild_kernel(
    const float* __restrict__ kg, const float* __restrict__ w1,
    ushort_t* __restrict__ ghi, ushort_t* __restrict__ glo)
{
    int j = blockIdx.x;
    __shared__ float ks[6144];
    __shared__ float w1s[9216];
    int tid = threadIdx.x;
    const float4* src = (const float4*)(kg + (size_t)j * 6144);
    #pragma unroll
    for (int r = 0; r < 6; ++r) ((float4*)ks)[tid + r * 256] = src[tid + r * 256];
    #pragma unroll
    for (int r = 0; r < 9; ++r) ((float4*)w1s)[tid + r * 256] = ((const float4*)w1)[tid + r * 256];
    __syncthreads();

    int d = tid & 63, tg = tid >> 6;
    for (int m = 0; m < 8; ++m)
        for (int kk = 0; kk < 8; ++kk)
            #pragma unroll
            for (int tt = 0; tt < 3; ++tt) {
                int t = tg * 3 + tt;
                const float* wrow = w1s + m * 1152 + kk * 144 + t * 12;
                const float* krow = ks + kk * 768 + d;
                float acc = 0.f;
                #pragma unroll
                for (int s = 0; s < 12; ++s) acc += wrow[s] * krow[s * 64];
                size_t o = (size_t)(j * 8 + m) * 6144 + kk * 768 + t * 64 + d;
                __hip_bfloat16 h = __float2bfloat16(acc);
                ghi[o] = *(ushort_t*)&h;
                glo[o] = bf16bits(acc - __bfloat162float(h));
            }
}

// ---------------------------------------------------------------- K3: H GEMM (MFMA bf16, 3-term split, K-split)
// H_z[i][n] partial over K-range; z: p = z>>1 in {QhiGhi, QhiGlo, QloGhi}, khalf = z&1
// block tile 64(M) x 128(N) x BK=64; 4 waves, wave tile 32x64
__global__ __launch_bounds__(256) void hgemm_kernel(
    const ushort_t* __restrict__ qhi, const ushort_t* __restrict__ qlo,
    const ushort_t* __restrict__ ghi, const ushort_t* __restrict__ glo,
    float* __restrict__ hpart)
{
    __shared__ ushort_t As[2][64 * 64];
    __shared__ ushort_t Bs[2][128 * 64];

    int tid = threadIdx.x;
    int lane = tid & 63, wid = tid >> 6;
    int wr = wid >> 1, wc = wid & 1;
    int n0 = blockIdx.x * 128, i0 = blockIdx.y * 64;
    int z = blockIdx.z, p = z >> 1;
    int kbase = (z & 1) * 3072;
    const ushort_t* Aptr = (p < 2) ? qhi : qlo;
    const ushort_t* Bptr = (p == 1) ? glo : ghi;
    float* Hout = hpart + (size_t)z * 524288;

    f32x4 acc[2][4] = {};

    // staging: LDS linear dest (chunk*16B), global source column pre-swizzled
    #define STAGE(buf, k0)                                                              \
    {                                                                                   \
        _Pragma("unroll")                                                               \
        for (int r = 0; r < 2; ++r) {                                                   \
            int c = r * 256 + tid; int row = c >> 3, slot = c & 7;                      \
            const ushort_t* g = Aptr + (size_t)(i0 + row) * 6144 + (k0) + ((slot ^ (row & 7)) * 8); \
            GLOAD16(g, &As[buf][c * 8]);                                                \
        }                                                                               \
        _Pragma("unroll")                                                               \
        for (int r = 0; r < 4; ++r) {                                                   \
            int c = r * 256 + tid; int row = c >> 3, slot = c & 7;                      \
            const ushort_t* g = Bptr + (size_t)(n0 + row) * 6144 + (k0) + ((slot ^ (row & 7)) * 8); \
            GLOAD16(g, &Bs[buf][c * 8]);                                                \
        }                                                                               \
    }

    STAGE(0, kbase);
    int cur = 0;
    for (int step = 0; step < 48; ++step) {
        __syncthreads();
        if (step + 1 < 48) { STAGE(cur ^ 1, kbase + (step + 1) * 64); }
        #pragma unroll
        for (int kh = 0; kh < 2; ++kh) {
            bf16x8 a[2], b[4];
            #pragma unroll
            for (int mi = 0; mi < 2; ++mi) {
                int row = wr * 32 + mi * 16 + (lane & 15);
                int slot = (kh * 4 + (lane >> 4)) ^ (row & 7);
                a[mi] = *(const bf16x8*)&As[cur][row * 64 + slot * 8];
            }
            #pragma unroll
            for (int ni = 0; ni < 4; ++ni) {
                int row = wc * 64 + ni * 16 + (lane & 15);
                int slot = (kh * 4 + (lane >> 4)) ^ (row & 7);
                b[ni] = *(const bf16x8*)&Bs[cur][row * 64 + slot * 8];
            }
            #pragma unroll
            for (int mi = 0; mi < 2; ++mi)
                #pragma unroll
                for (int ni = 0; ni < 4; ++ni)
                    acc[mi][ni] = __builtin_amdgcn_mfma_f32_16x16x32_bf16(a[mi], b[ni], acc[mi][ni], 0, 0, 0);
        }
        cur ^= 1;
    }

    // epilogue: C layout col=lane&15, row=(lane>>4)*4+reg  [m89-verified]
    int r4 = (lane >> 4) * 4, cn = lane & 15;
    #pragma unroll
    for (int mi = 0; mi < 2; ++mi)
        #pragma unroll
        for (int ni = 0; ni < 4; ++ni)
            #pragma unroll
            for (int r = 0; r < 4; ++r) {
                int row = i0 + wr * 32 + mi * 16 + r4 + r;
                int col = n0 + wc * 64 + ni * 16 + cn;
                Hout[(size_t)row * 2048 + col] = acc[mi][ni][r];
            }
    #undef STAGE
}

// ---------------------------------------------------------------- K4: score epilogue + softmax
__global__ __launch_bounds__(256) void score_softmax_kernel(
    const float* __restrict__ hpart, const float* __restrict__ b1g,
    const float* __restrict__ w2g, const float* __restrict__ b2g,
    float* __restrict__ att)
{
    int i = blockIdx.x, j = threadIdx.x;
    float hm[8];
    #pragma unroll
    for (int m = 0; m < 8; ++m) hm[m] = b1g[m];
    #pragma unroll
    for (int z = 0; z < 6; ++z) {
        const float4* p = (const float4*)(hpart + (size_t)z * 524288 + (size_t)i * 2048 + j * 8);
        float4 x0 = p[0], x1 = p[1];
        hm[0] += x0.x; hm[1] += x0.y; hm[2] += x0.z; hm[3] += x0.w;
        hm[4] += x1.x; hm[5] += x1.y; hm[6] += x1.z; hm[7] += x1.w;
    }
    float sv = b2g[0];
    #pragma unroll
    for (int m = 0; m < 8; ++m) sv += fmaxf(hm[m], 0.f) * w2g[m];

    __shared__ float wred[4], wred2[4];
    float mx = sv;
    #pragma unroll
    for (int off = 32; off > 0; off >>= 1) mx = fmaxf(mx, __shfl_down(mx, off, 64));
    if ((j & 63) == 0) wred[j >> 6] = mx;
    __syncthreads();
    mx = fmaxf(fmaxf(wred[0], wred[1]), fmaxf(wred[2], wred[3]));

    float e = expf(sv - mx);
    float sum = e;
    #pragma unroll
    for (int off = 32; off > 0; off >>= 1) sum += __shfl_down(sum, off, 64);
    if ((j & 63) == 0) wred2[j >> 6] = sum;
    __syncthreads();
    sum = wred2[0] + wred2[1] + wred2[2] + wred2[3];

    att[(size_t)i * 256 + j] = e / sum;
}

// ---------------------------------------------------------------- K5: b = att @ v
__global__ __launch_bounds__(256) void av_kernel(
    const float* __restrict__ att, const float* __restrict__ vg, float* __restrict__ bmat)
{
    int t = blockIdx.x >> 1, half = blockIdx.x & 1, itile = blockIdx.y;
    int tid = threadIdx.x;
    __shared__ float atts[256 * 16];
    #pragma unroll
    for (int r = 0; r < 16; ++r) {
        int e = tid + r * 256;
        int j = e >> 4, iiq = e & 15;
        atts[e] = att[(size_t)(itile * 16 + iiq) * 256 + j];
    }
    __syncthreads();

    int kk = tid >> 5;
    int d  = (tid & 31) + half * 32;
    float acc[16] = {0.f,0.f,0.f,0.f,0.f,0.f,0.f,0.f,0.f,0.f,0.f,0.f,0.f,0.f,0.f,0.f};
    const float* vp = vg + (size_t)kk * 768 + t * 64 + d;
    #pragma unroll 4
    for (int j = 0; j < 256; ++j) {
        float vv = vp[(size_t)j * 6144];
        const float4* ap = (const float4*)(atts + j * 16);
        #pragma unroll
        for (int g = 0; g < 4; ++g) {
            float4 a = ap[g];
            acc[g*4+0] += a.x * vv; acc[g*4+1] += a.y * vv;
            acc[g*4+2] += a.z * vv; acc[g*4+3] += a.w * vv;
        }
    }
    #pragma unroll
    for (int iiq = 0; iiq < 16; ++iiq)
        bmat[(((size_t)(itile * 16 + iiq) * 12 + t) * 8 + kk) * 64 + d] = acc[iiq];
}

// ---------------------------------------------------------------- K6: y = relu(b@w3T+b3)@w4T+b4
__global__ __launch_bounds__(64) void out_kernel(
    const float* __restrict__ bmat, const float* __restrict__ w3t, const float* __restrict__ b3,
    const float* __restrict__ w4t, const float* __restrict__ b4, float* __restrict__ yout)
{
    int rb = blockIdx.x * 8;
    int tid = threadIdx.x;
    __shared__ float rows[8 * 512];
    __shared__ float y1s[8 * 64];
    const float4* src = (const float4*)(bmat + (size_t)rb * 512);
    #pragma unroll
    for (int r = 0; r < 16; ++r) ((float4*)rows)[tid + r * 64] = src[tid + r * 64];
    __syncthreads();

    float acc[8];
    float b3v = b3[tid];
    #pragma unroll
    for (int r = 0; r < 8; ++r) acc[r] = b3v;
    for (int c = 0; c < 512; ++c) {
        float wv = w3t[c * 64 + tid];
        int rowidx = ((c & 7) << 6) | (c >> 3);
        #pragma unroll
        for (int r = 0; r < 8; ++r) acc[r] += rows[r * 512 + rowidx] * wv;
    }
    #pragma unroll
    for (int r = 0; r < 8; ++r) y1s[r * 64 + tid] = fmaxf(acc[r], 0.f);
    __syncthreads();

    int f = tid & 31, rg = tid >> 5;
    #pragma unroll
    for (int rr = 0; rr < 4; ++rr) {
        int r = rg * 4 + rr;
        float a2 = b4[f];
        #pragma unroll
        for (int d = 0; d < 64; ++d) a2 += y1s[r * 64 + d] * w4t[d * 32 + f];
        yout[(size_t)(rb + r) * 32 + f] = a2;
    }
}

// ---------------------------------------------------------------- launch
extern "C" void kernel_launch(void* const* d_in, const int* in_sizes, int n_in,
                              void* d_out, int out_size, void* d_ws, size_t ws_size,
                              hipStream_t stream) {
    (void)in_sizes; (void)n_in; (void)out_size; (void)ws_size;
    const float* x  = (const float*)d_in[0];
    const float* Wq = (const float*)d_in[1];
    const float* Wk = (const float*)d_in[2];
    const float* Wv = (const float*)d_in[3];
    const float* bq = (const float*)d_in[4];
    const float* bk = (const float*)d_in[5];
    const float* bv = (const float*)d_in[6];
    const float* w1 = (const float*)d_in[7];
    const float* b1 = (const float*)d_in[8];
    const float* w2 = (const float*)d_in[9];
    const float* b2 = (const float*)d_in[10];
    const float* w3 = (const float*)d_in[11];
    const float* b3 = (const float*)d_in[12];
    const float* w4 = (const float*)d_in[13];
    const float* b4 = (const float*)d_in[14];

    float* ws = (float*)d_ws;
    // layout (floats); hpart overlaps [k | bmat] (k dead after gbuild; bmat written after hpart consumed)
    float*    kbuf = ws;                          // 1,572,864
    float*    bmat = ws + 1572864;                // 1,572,864
    float*    hpart= ws;                          // 3,145,728 (= k + bmat regions)
    float*    v    = ws + 3145728;                // 1,572,864
    ushort_t* qhi  = (ushort_t*)(ws + 4718592);   // 1,572,864 ushorts
    ushort_t* qlo  = (ushort_t*)(ws + 5505024);
    ushort_t* ghi  = (ushort_t*)(ws + 6291456);   // 12,582,912 ushorts
    ushort_t* glo  = (ushort_t*)(ws + 12582912);
    float*    w3t  = ws + 18874368;               // 32,768
    float*    w4t  = ws + 18907136;               // 2,048

    float* yout = (float*)d_out;              // 98304
    float* att  = (float*)d_out + 98304;      // 65536

    transpose_w_kernel<<<128, 256, 0, stream>>>(w3, w4, w3t, w4t);
    qkv_kernel<<<2048, 256, 0, stream>>>(x, Wq, Wk, Wv, bq, bk, bv, qhi, qlo, kbuf, v);
    gbuild_kernel<<<256, 256, 0, stream>>>(kbuf, w1, ghi, glo);
    hgemm_kernel<<<dim3(16, 4, 6), 256, 0, stream>>>(qhi, qlo, ghi, glo, hpart);
    score_softmax_kernel<<<256, 256, 0, stream>>>(hpart, b1, w2, b2, att);
    av_kernel<<<dim3(24, 16), 256, 0, stream>>>(att, v, bmat);
    out_kernel<<<384, 64, 0, stream>>>(bmat, w3t, b3, w4t, b4, yout);
}

// Round 3
// 116.764 us; speedup vs baseline: 3.0928x; 1.3612x over previous
//
#include <hip/hip_runtime.h>
#include <hip/hip_bf16.h>

// N=256, T=12, F=32, T_dim=8, D=64;  c-index: c = kk*768 + t*64 + d  (size 6144)
typedef unsigned short ushort_t;
typedef __bf16 bf16x8 __attribute__((ext_vector_type(8)));
typedef float f32x4 __attribute__((ext_vector_type(4)));

#define GLOAD16(gp, lp) \
    __builtin_amdgcn_global_load_lds((const __attribute__((address_space(1))) void*)(gp), \
                                     (__attribute__((address_space(3))) void*)(lp), 16, 0, 0)

__device__ __forceinline__ ushort_t bf16bits(float x) {
    __hip_bfloat16 h = __float2bfloat16(x);
    return *(ushort_t*)&h;
}

// ---------------------------------------------------------------- K1: QKV projection (+ Q split hi/lo scaled 0.125)
__global__ __launch_bounds__(256) void qkv_kernel(
    const float* __restrict__ x,
    const float* __restrict__ Wq, const float* __restrict__ Wk, const float* __restrict__ Wv,
    const float* __restrict__ bq, const float* __restrict__ bk, const float* __restrict__ bv,
    ushort_t* __restrict__ qhi, ushort_t* __restrict__ qlo,
    float* __restrict__ k, float* __restrict__ v)
{
    int b = blockIdx.x;          // 0..2047
    int n = b >> 3;
    __shared__ float xs[384];
    int tid = threadIdx.x;
    if (tid < 96) ((float4*)xs)[tid] = ((const float4*)(x + n * 384))[tid];
    __syncthreads();

    int d = tid & 63, tg = tid >> 6;
    const float* wqb = Wq + (size_t)b * 2048 + d;
    const float* wkb = Wk + (size_t)b * 2048 + d;
    const float* wvb = Wv + (size_t)b * 2048 + d;
    float aq[3] = {0.f,0.f,0.f}, ak[3] = {0.f,0.f,0.f}, av[3] = {0.f,0.f,0.f};
    #pragma unroll 8
    for (int f = 0; f < 32; ++f) {
        float wq = wqb[f * 64], wk = wkb[f * 64], wv = wvb[f * 64];
        #pragma unroll
        for (int tt = 0; tt < 3; ++tt) {
            float xv = xs[(tg + tt * 4) * 32 + f];
            aq[tt] += xv * wq; ak[tt] += xv * wk; av[tt] += xv * wv;
        }
    }
    float bqv = bq[b * 64 + d], bkv = bk[b * 64 + d], bvv = bv[b * 64 + d];
    #pragma unroll
    for (int tt = 0; tt < 3; ++tt) {
        int t = tg + tt * 4;
        size_t o = ((size_t)b * 12 + t) * 64 + d;
        float qs = 0.125f * (aq[tt] + bqv);
        __hip_bfloat16 qh = __float2bfloat16(qs);
        qhi[o] = *(ushort_t*)&qh;
        qlo[o] = bf16bits(qs - __bfloat162float(qh));
        k[o] = ak[tt] + bkv;
        v[o] = av[tt] + bvv;
    }
}

// ---------------------------------------------------------------- K2: G build (512 blocks: j x kk-half)
// G[(j*8+m)][kk*768+t*64+d] = sum_s w1[m][kk*144+t*12+s] * k[j*8+kk][s][d], bf16 hi/lo
__global__ __launch_bounds__(256) void gbuild_kernel(
    const float* __restrict__ kg, const float* __restrict__ w1,
    ushort_t* __restrict__ ghi, ushort_t* __restrict__ glo)
{
    int j = blockIdx.x >> 1, kh = (blockIdx.x & 1) * 4;
    __shared__ float ks[4 * 12 * 64];     // 4 kk rows
    int tid = threadIdx.x;
    const float4* src = (const float4*)(kg + ((size_t)j * 8 + kh) * 768);
    #pragma unroll
    for (int r = 0; r < 3; ++r) ((float4*)ks)[tid + r * 256] = src[tid + r * 256];
    __syncthreads();

    int d = tid & 63, tg = tid >> 6;
    #pragma unroll
    for (int kkl = 0; kkl < 4; ++kkl) {
        float kreg[12];
        #pragma unroll
        for (int s = 0; s < 12; ++s) kreg[s] = ks[(kkl * 12 + s) * 64 + d];
        int kk = kh + kkl;
        for (int m = 0; m < 8; ++m) {
            const float* w1p = w1 + m * 1152 + kk * 144;   // + t*12 + s  (wave-uniform)
            #pragma unroll
            for (int tt = 0; tt < 3; ++tt) {
                int t = tg * 3 + tt;
                float acc = 0.f;
                #pragma unroll
                for (int s = 0; s < 12; ++s) acc += w1p[t * 12 + s] * kreg[s];
                size_t o = ((size_t)j * 8 + m) * 6144 + kk * 768 + t * 64 + d;
                __hip_bfloat16 h = __float2bfloat16(acc);
                ghi[o] = *(ushort_t*)&h;
                glo[o] = bf16bits(acc - __bfloat162float(h));
            }
        }
    }
}

// ---------------------------------------------------------------- K3: transpose v (fp32 [j][c] -> bf16 vt[c][j]) + w3/w4 prep
__global__ __launch_bounds__(256) void transpose_wv_kernel(
    const float* __restrict__ v, const float* __restrict__ w3, const float* __restrict__ w4,
    ushort_t* __restrict__ vt, float* __restrict__ w3t, float* __restrict__ w4t)
{
    int bx = blockIdx.x, tid = threadIdx.x;
    if (bx >= 96) {
        // w3 (64 dout x 512 c3, c3=d*8+kk) -> w3t[cb*64+dout], cb = kk*64+d (bmat order)
        int base = (bx - 96) * 16384;
        for (int r = 0; r < 64; ++r) {
            int e = base + r * 256 + tid;
            int dout = e >> 9, c3 = e & 511;
            int cb = ((c3 & 7) << 6) | (c3 >> 3);
            w3t[cb * 64 + dout] = w3[e];
        }
        if (bx == 96) {
            #pragma unroll
            for (int r = 0; r < 8; ++r) {
                int e = r * 256 + tid; int f = e >> 6, d = e & 63;
                w4t[d * 32 + f] = w4[e];
            }
        }
        return;
    }
    __shared__ ushort_t ts[64][258];
    int c0 = bx * 64;
    int cc = tid & 63, jg = tid >> 6;
    for (int jj = 0; jj < 64; ++jj) {
        int j = jg * 64 + jj;
        ts[cc][j] = bf16bits(v[(size_t)j * 6144 + c0 + cc]);
    }
    __syncthreads();
    for (int c = 0; c < 64; ++c)
        vt[(size_t)(c0 + c) * 256 + tid] = ts[c][tid];
}

// ---------------------------------------------------------------- K4: H GEMM (3 products fused, z = pure K-split)
// block 128x128, 4 waves (2x2) of 64x64; BK=64 dbuf; steps = 3 * (kspan/64)
__global__ __launch_bounds__(256, 2) void hgemm_kernel(
    const ushort_t* __restrict__ qhi, const ushort_t* __restrict__ qlo,
    const ushort_t* __restrict__ ghi, const ushort_t* __restrict__ glo,
    float* __restrict__ hpart, int kspan)
{
    __shared__ ushort_t As[2][128 * 64];
    __shared__ ushort_t Bs[2][128 * 64];

    int tid = threadIdx.x, lane = tid & 63, wid = tid >> 6;
    int wr = wid >> 1, wc = wid & 1;
    int n0 = blockIdx.x * 128, i0 = blockIdx.y * 128, z = blockIdx.z;
    int kbase = z * kspan;
    int spp = kspan >> 6;
    int nsteps = spp * 3;
    float* Hout = hpart + (size_t)z * 524288;

    f32x4 acc[4][4] = {};

    #define STAGE(buf, Ap, Bp, koff)                                                        \
    {                                                                                       \
        _Pragma("unroll")                                                                   \
        for (int r = 0; r < 4; ++r) {                                                       \
            int c = r * 256 + tid; int row = c >> 3, slot = c & 7;                          \
            GLOAD16(Ap + (size_t)(i0 + row) * 6144 + (koff) + ((slot ^ (row & 7)) * 8),     \
                    &As[buf][c * 8]);                                                       \
        }                                                                                   \
        _Pragma("unroll")                                                                   \
        for (int r = 0; r < 4; ++r) {                                                       \
            int c = r * 256 + tid; int row = c >> 3, slot = c & 7;                          \
            GLOAD16(Bp + (size_t)(n0 + row) * 6144 + (koff) + ((slot ^ (row & 7)) * 8),     \
                    &Bs[buf][c * 8]);                                                       \
        }                                                                                   \
    }

    int cur = 0, p = 0, ks = 0;
    STAGE(0, qhi, ghi, kbase);
    for (int s = 0; s < nsteps; ++s) {
        int pn = p, ksn = ks + 1;
        if (ksn == spp) { ksn = 0; pn = p + 1; }
        __syncthreads();
        if (s + 1 < nsteps) {
            const ushort_t* An = (pn == 2) ? qlo : qhi;
            const ushort_t* Bn = (pn == 1) ? glo : ghi;
            STAGE(cur ^ 1, An, Bn, kbase + ksn * 64);
        }
        #pragma unroll
        for (int kh = 0; kh < 2; ++kh) {
            bf16x8 a[4], b[4];
            #pragma unroll
            for (int mi = 0; mi < 4; ++mi) {
                int row = wr * 64 + mi * 16 + (lane & 15);
                int slot = (kh * 4 + (lane >> 4)) ^ (row & 7);
                a[mi] = *(const bf16x8*)&As[cur][row * 64 + slot * 8];
            }
            #pragma unroll
            for (int ni = 0; ni < 4; ++ni) {
                int row = wc * 64 + ni * 16 + (lane & 15);
                int slot = (kh * 4 + (lane >> 4)) ^ (row & 7);
                b[ni] = *(const bf16x8*)&Bs[cur][row * 64 + slot * 8];
            }
            #pragma unroll
            for (int mi = 0; mi < 4; ++mi)
                #pragma unroll
                for (int ni = 0; ni < 4; ++ni)
                    acc[mi][ni] = __builtin_amdgcn_mfma_f32_16x16x32_bf16(a[mi], b[ni], acc[mi][ni], 0, 0, 0);
        }
        cur ^= 1; p = pn; ks = ksn;
    }
    #undef STAGE

    int r4 = (lane >> 4) * 4, cn = lane & 15;
    #pragma unroll
    for (int mi = 0; mi < 4; ++mi)
        #pragma unroll
        for (int ni = 0; ni < 4; ++ni)
            #pragma unroll
            for (int r = 0; r < 4; ++r) {
                int row = i0 + wr * 64 + mi * 16 + r4 + r;
                int col = n0 + wc * 64 + ni * 16 + cn;
                Hout[(size_t)row * 2048 + col] = acc[mi][ni][r];
            }
}

// ---------------------------------------------------------------- K5: score epilogue + softmax (+ bf16 att)
__global__ __launch_bounds__(256) void score_softmax_kernel(
    const float* __restrict__ hpart, const float* __restrict__ b1g,
    const float* __restrict__ w2g, const float* __restrict__ b2g,
    float* __restrict__ att, ushort_t* __restrict__ attbf, int nz)
{
    int i = blockIdx.x, j = threadIdx.x;
    float hm[8];
    #pragma unroll
    for (int m = 0; m < 8; ++m) hm[m] = b1g[m];
    for (int z = 0; z < nz; ++z) {
        const float4* p = (const float4*)(hpart + (size_t)z * 524288 + (size_t)i * 2048 + j * 8);
        float4 x0 = p[0], x1 = p[1];
        hm[0] += x0.x; hm[1] += x0.y; hm[2] += x0.z; hm[3] += x0.w;
        hm[4] += x1.x; hm[5] += x1.y; hm[6] += x1.z; hm[7] += x1.w;
    }
    float sv = b2g[0];
    #pragma unroll
    for (int m = 0; m < 8; ++m) sv += fmaxf(hm[m], 0.f) * w2g[m];

    __shared__ float wred[4], wred2[4];
    float mx = sv;
    #pragma unroll
    for (int off = 32; off > 0; off >>= 1) mx = fmaxf(mx, __shfl_down(mx, off, 64));
    if ((j & 63) == 0) wred[j >> 6] = mx;
    __syncthreads();
    mx = fmaxf(fmaxf(wred[0], wred[1]), fmaxf(wred[2], wred[3]));

    float e = expf(sv - mx);
    float sum = e;
    #pragma unroll
    for (int off = 32; off > 0; off >>= 1) sum += __shfl_down(sum, off, 64);
    if ((j & 63) == 0) wred2[j >> 6] = sum;
    __syncthreads();
    sum = wred2[0] + wred2[1] + wred2[2] + wred2[3];

    float pv = e / sum;
    att[(size_t)i * 256 + j] = pv;
    attbf[(size_t)i * 256 + j] = bf16bits(pv);
}

// ---------------------------------------------------------------- K6: b = att @ v via MFMA
// M=256(i), N=6144(c), K=256(j); block 128x128, 4 waves 64x64; grid (48,2); 4 K-steps
__global__ __launch_bounds__(256) void av_kernel(
    const ushort_t* __restrict__ attbf, const ushort_t* __restrict__ vt,
    float* __restrict__ bmat)
{
    __shared__ ushort_t As[2][128 * 64];
    __shared__ ushort_t Bs[2][128 * 64];

    int tid = threadIdx.x, lane = tid & 63, wid = tid >> 6;
    int wr = wid >> 1, wc = wid & 1;
    int n0 = blockIdx.x * 128, i0 = blockIdx.y * 128;

    f32x4 acc[4][4] = {};

    #define STAGEAV(buf, koff)                                                              \
    {                                                                                       \
        _Pragma("unroll")                                                                   \
        for (int r = 0; r < 4; ++r) {                                                       \
            int c = r * 256 + tid; int row = c >> 3, slot = c & 7;                          \
            GLOAD16(attbf + (size_t)(i0 + row) * 256 + (koff) + ((slot ^ (row & 7)) * 8),   \
                    &As[buf][c * 8]);                                                       \
        }                                                                                   \
        _Pragma("unroll")                                                                   \
        for (int r = 0; r < 4; ++r) {                                                       \
            int c = r * 256 + tid; int row = c >> 3, slot = c & 7;                          \
            GLOAD16(vt + (size_t)(n0 + row) * 256 + (koff) + ((slot ^ (row & 7)) * 8),      \
                    &Bs[buf][c * 8]);                                                       \
        }                                                                                   \
    }

    int cur = 0;
    STAGEAV(0, 0);
    for (int s = 0; s < 4; ++s) {
        __syncthreads();
        if (s < 3) STAGEAV(cur ^ 1, (s + 1) * 64);
        #pragma unroll
        for (int kh = 0; kh < 2; ++kh) {
            bf16x8 a[4], b[4];
            #pragma unroll
            for (int mi = 0; mi < 4; ++mi) {
                int row = wr * 64 + mi * 16 + (lane & 15);
                int slot = (kh * 4 + (lane >> 4)) ^ (row & 7);
                a[mi] = *(const bf16x8*)&As[cur][row * 64 + slot * 8];
            }
            #pragma unroll
            for (int ni = 0; ni < 4; ++ni) {
                int row = wc * 64 + ni * 16 + (lane & 15);
                int slot = (kh * 4 + (lane >> 4)) ^ (row & 7);
                b[ni] = *(const bf16x8*)&Bs[cur][row * 64 + slot * 8];
            }
            #pragma unroll
            for (int mi = 0; mi < 4; ++mi)
                #pragma unroll
                for (int ni = 0; ni < 4; ++ni)
                    acc[mi][ni] = __builtin_amdgcn_mfma_f32_16x16x32_bf16(a[mi], b[ni], acc[mi][ni], 0, 0, 0);
        }
        cur ^= 1;
    }
    #undef STAGEAV

    // write bmat[(i*12+t)*512 + kk*64 + d], c = kk*768+t*64+d
    int r4 = (lane >> 4) * 4, cn = lane & 15;
    #pragma unroll
    for (int mi = 0; mi < 4; ++mi)
        #pragma unroll
        for (int ni = 0; ni < 4; ++ni) {
            int c = n0 + wc * 64 + ni * 16 + cn;
            int kk = c / 768, rem = c - kk * 768;
            int t = rem >> 6, d = rem & 63;
            #pragma unroll
            for (int r = 0; r < 4; ++r) {
                int row = i0 + wr * 64 + mi * 16 + r4 + r;
                bmat[((size_t)row * 12 + t) * 512 + kk * 64 + d] = acc[mi][ni][r];
            }
        }
}

// ---------------------------------------------------------------- K7: y = relu(b@w3T+b3)@w4T+b4 (16 rows/block)
__global__ __launch_bounds__(256) void out_kernel(
    const float* __restrict__ bmat, const float* __restrict__ w3t, const float* __restrict__ b3,
    const float* __restrict__ w4t, const float* __restrict__ b4, float* __restrict__ yout)
{
    int rb = blockIdx.x * 16;     // rows (i*12+t)
    int tid = threadIdx.x;
    __shared__ float rows[16 * 512];
    __shared__ float y1s[16 * 64];
    const float4* src = (const float4*)(bmat + (size_t)rb * 512);
    #pragma unroll
    for (int r = 0; r < 8; ++r) ((float4*)rows)[tid + r * 256] = src[tid + r * 256];
    __syncthreads();

    int dout = tid & 63, rg = tid >> 6;
    float acc[4];
    float b3v = b3[dout];
    #pragma unroll
    for (int jj = 0; jj < 4; ++jj) acc[jj] = b3v;
    for (int c4 = 0; c4 < 128; ++c4) {
        float w0 = w3t[(c4 * 4 + 0) * 64 + dout];
        float w1v = w3t[(c4 * 4 + 1) * 64 + dout];
        float w2v = w3t[(c4 * 4 + 2) * 64 + dout];
        float w3v = w3t[(c4 * 4 + 3) * 64 + dout];
        #pragma unroll
        for (int jj = 0; jj < 4; ++jj) {
            float4 rv = *(const float4*)&rows[(rg * 4 + jj) * 512 + c4 * 4];
            acc[jj] += rv.x * w0 + rv.y * w1v + rv.z * w2v + rv.w * w3v;
        }
    }
    #pragma unroll
    for (int jj = 0; jj < 4; ++jj) y1s[(rg * 4 + jj) * 64 + dout] = fmaxf(acc[jj], 0.f);
    __syncthreads();

    int f = tid & 31, rh = tid >> 5;
    #pragma unroll
    for (int rr = 0; rr < 2; ++rr) {
        int r = rh * 2 + rr;
        float a2 = b4[f];
        #pragma unroll
        for (int dd = 0; dd < 64; ++dd) a2 += y1s[r * 64 + dd] * w4t[dd * 32 + f];
        yout[(size_t)(rb + r) * 32 + f] = a2;
    }
}

// ---------------------------------------------------------------- launch
extern "C" void kernel_launch(void* const* d_in, const int* in_sizes, int n_in,
                              void* d_out, int out_size, void* d_ws, size_t ws_size,
                              hipStream_t stream) {
    (void)in_sizes; (void)n_in; (void)out_size;
    const float* x  = (const float*)d_in[0];
    const float* Wq = (const float*)d_in[1];
    const float* Wk = (const float*)d_in[2];
    const float* Wv = (const float*)d_in[3];
    const float* bq = (const float*)d_in[4];
    const float* bk = (const float*)d_in[5];
    const float* bv = (const float*)d_in[6];
    const float* w1 = (const float*)d_in[7];
    const float* b1 = (const float*)d_in[8];
    const float* w2 = (const float*)d_in[9];
    const float* b2 = (const float*)d_in[10];
    const float* w3 = (const float*)d_in[11];
    const float* b3 = (const float*)d_in[12];
    const float* w4 = (const float*)d_in[13];
    const float* b4 = (const float*)d_in[14];

    // K-split factor chosen by available workspace
    int nz;
    if      (ws_size >= (size_t)23398400 * 4) nz = 16;
    else if (ws_size >= (size_t)19204096 * 4) nz = 8;
    else                                      nz = 4;
    size_t hp = (size_t)nz * 524288;                    // hpart floats

    float* ws = (float*)d_ws;
    float*    kbuf  = ws;                                // [0, 1572864) — dead after gbuild
    float*    vbuf  = ws + 1572864;                      // [1572864, 3145728) — dead after transpose
    float*    hpart = ws;                                // overlaps kbuf+v (both dead before hgemm)
    size_t    off   = (hp > 3145728) ? hp : 3145728;
    ushort_t* qhi   = (ushort_t*)(ws + off);             // 1572864 ushorts
    ushort_t* qlo   = (ushort_t*)(ws + off + 786432);
    ushort_t* ghi   = (ushort_t*)(ws + off + 1572864);   // 12582912 ushorts
    ushort_t* glo   = (ushort_t*)(ws + off + 7864320);
    ushort_t* vt    = (ushort_t*)(ws + off + 14155776);  // 1572864 ushorts
    ushort_t* attbf = (ushort_t*)(ws + off + 14942208);  // 65536 ushorts
    float*    w3t   = ws + off + 14974976;               // 32768
    float*    w4t   = ws + off + 15007744;               // 2048
    float*    bmat  = (float*)ghi;                       // reuse ghi region (dead after hgemm)

    float* yout = (float*)d_out;              // 98304
    float* att  = (float*)d_out + 98304;      // 65536

    qkv_kernel<<<2048, 256, 0, stream>>>(x, Wq, Wk, Wv, bq, bk, bv, qhi, qlo, kbuf, vbuf);
    gbuild_kernel<<<512, 256, 0, stream>>>(kbuf, w1, ghi, glo);
    transpose_wv_kernel<<<98, 256, 0, stream>>>(vbuf, w3, w4, vt, w3t, w4t);
    hgemm_kernel<<<dim3(16, 2, nz), 256, 0, stream>>>(qhi, qlo, ghi, glo, hpart, 6144 / nz);
    score_softmax_kernel<<<256, 256, 0, stream>>>(hpart, b1, w2, b2, att, attbf, nz);
    av_kernel<<<dim3(48, 2), 256, 0, stream>>>(attbf, vt, bmat);
    out_kernel<<<192, 256, 0, stream>>>(bmat, w3t, b3, w4t, b4, yout);
}

// Round 4
// 114.883 us; speedup vs baseline: 3.1435x; 1.0164x over previous
//
#include <hip/hip_runtime.h>
#include <hip/hip_bf16.h>

// N=256, T=12, F=32, T_dim=8, D=64;  c-index: c = kk*768 + t*64 + d  (size 6144)
typedef unsigned short ushort_t;
typedef __bf16 bf16x8 __attribute__((ext_vector_type(8)));
typedef float f32x4 __attribute__((ext_vector_type(4)));

#define GLOAD16(gp, lp) \
    __builtin_amdgcn_global_load_lds((const __attribute__((address_space(1))) void*)(gp), \
                                     (__attribute__((address_space(3))) void*)(lp), 16, 0, 0)

__device__ __forceinline__ ushort_t bf16bits(float x) {
    __hip_bfloat16 h = __float2bfloat16(x);
    return *(ushort_t*)&h;
}
__device__ __forceinline__ float bf2f(ushort_t u) {
    unsigned v = (unsigned)u << 16;
    float f;
    __builtin_memcpy(&f, &v, 4);
    return f;
}

// ---------------------------------------------------------------- K1: QKV projection (+ Q split hi/lo scaled 0.125)
__global__ __launch_bounds__(256) void qkv_kernel(
    const float* __restrict__ x,
    const float* __restrict__ Wq, const float* __restrict__ Wk, const float* __restrict__ Wv,
    const float* __restrict__ bq, const float* __restrict__ bk, const float* __restrict__ bv,
    ushort_t* __restrict__ qhi, ushort_t* __restrict__ qlo,
    float* __restrict__ k, float* __restrict__ v)
{
    int b = blockIdx.x;          // 0..2047
    int n = b >> 3;
    __shared__ float xs[384];
    int tid = threadIdx.x;
    if (tid < 96) ((float4*)xs)[tid] = ((const float4*)(x + n * 384))[tid];
    __syncthreads();

    int d = tid & 63, tg = tid >> 6;
    const float* wqb = Wq + (size_t)b * 2048 + d;
    const float* wkb = Wk + (size_t)b * 2048 + d;
    const float* wvb = Wv + (size_t)b * 2048 + d;
    float aq[3] = {0.f,0.f,0.f}, ak[3] = {0.f,0.f,0.f}, av[3] = {0.f,0.f,0.f};
    #pragma unroll 8
    for (int f = 0; f < 32; ++f) {
        float wq = wqb[f * 64], wk = wkb[f * 64], wv = wvb[f * 64];
        #pragma unroll
        for (int tt = 0; tt < 3; ++tt) {
            float xv = xs[(tg + tt * 4) * 32 + f];
            aq[tt] += xv * wq; ak[tt] += xv * wk; av[tt] += xv * wv;
        }
    }
    float bqv = bq[b * 64 + d], bkv = bk[b * 64 + d], bvv = bv[b * 64 + d];
    #pragma unroll
    for (int tt = 0; tt < 3; ++tt) {
        int t = tg + tt * 4;
        size_t o = ((size_t)b * 12 + t) * 64 + d;
        float qs = 0.125f * (aq[tt] + bqv);
        __hip_bfloat16 qh = __float2bfloat16(qs);
        qhi[o] = *(ushort_t*)&qh;
        qlo[o] = bf16bits(qs - __bfloat162float(qh));
        k[o] = ak[tt] + bkv;
        v[o] = av[tt] + bvv;
    }
}

// ---------------------------------------------------------------- K2: G build (blocks 0..511) + v transpose (512..607) + w prep (608)
// G[(j*8+m)][kk*768+t*64+d] = sum_s w1[m][kk*144+t*12+s] * k[j*8+kk][s][d], single bf16
__global__ __launch_bounds__(256) void gbuild_kernel(
    const float* __restrict__ kg, const float* __restrict__ w1,
    const float* __restrict__ v, const float* __restrict__ w3, const float* __restrict__ w4,
    ushort_t* __restrict__ ghi, ushort_t* __restrict__ vt,
    float* __restrict__ w3t, float* __restrict__ w4t)
{
    __shared__ char sbuf[64 * 258 * 2];   // union: ks (12 KB) | ts (33 KB)
    int bx = blockIdx.x, tid = threadIdx.x;

    if (bx >= 608) {
        // w3 (64 dout x 512 c3, c3=d*8+kk) -> w3t[cb*64+dout], cb = kk*64+d
        for (int r = 0; r < 128; ++r) {
            int e = r * 256 + tid;
            int dout = e >> 9, c3 = e & 511;
            int cb = ((c3 & 7) << 6) | (c3 >> 3);
            w3t[cb * 64 + dout] = w3[e];
        }
        #pragma unroll
        for (int r = 0; r < 8; ++r) {
            int e = r * 256 + tid; int f = e >> 6, d = e & 63;
            w4t[d * 32 + f] = w4[e];
        }
        return;
    }
    if (bx >= 512) {
        // v (fp32 [j][c]) -> bf16 vt[c][j], 64 c per block
        ushort_t (*ts)[258] = (ushort_t(*)[258])sbuf;
        int c0 = (bx - 512) * 64;
        int cc = tid & 63, jg = tid >> 6;
        for (int jj = 0; jj < 64; ++jj) {
            int j = jg * 64 + jj;
            ts[cc][j] = bf16bits(v[(size_t)j * 6144 + c0 + cc]);
        }
        __syncthreads();
        for (int c = 0; c < 64; ++c)
            vt[(size_t)(c0 + c) * 256 + tid] = ts[c][tid];
        return;
    }

    int j = bx >> 1, kh = (bx & 1) * 4;
    float* ks = (float*)sbuf;             // 4 kk rows: 3072 floats
    const float4* src = (const float4*)(kg + ((size_t)j * 8 + kh) * 768);
    #pragma unroll
    for (int r = 0; r < 3; ++r) ((float4*)ks)[tid + r * 256] = src[tid + r * 256];
    __syncthreads();

    int d = tid & 63, tg = tid >> 6;
    #pragma unroll
    for (int kkl = 0; kkl < 4; ++kkl) {
        float kreg[12];
        #pragma unroll
        for (int s = 0; s < 12; ++s) kreg[s] = ks[(kkl * 12 + s) * 64 + d];
        int kk = kh + kkl;
        for (int m = 0; m < 8; ++m) {
            const float* w1p = w1 + m * 1152 + kk * 144;   // wave-uniform
            #pragma unroll
            for (int tt = 0; tt < 3; ++tt) {
                int t = tg * 3 + tt;
                float acc = 0.f;
                #pragma unroll
                for (int s = 0; s < 12; ++s) acc += w1p[t * 12 + s] * kreg[s];
                size_t o = ((size_t)j * 8 + m) * 6144 + kk * 768 + t * 64 + d;
                ghi[o] = bf16bits(acc);
            }
        }
    }
}

// ---------------------------------------------------------------- K3: H GEMM
// H[i][(j,m)] = (Qhi+Qlo) . G ; block 128x128, 4 waves 64x64, BK=32, nz=16 K-split
// products share B-tile and accumulator; hpart output bf16
__global__ __launch_bounds__(256, 2) void hgemm_kernel(
    const ushort_t* __restrict__ qhi, const ushort_t* __restrict__ qlo,
    const ushort_t* __restrict__ ghi, ushort_t* __restrict__ hpart)
{
    __shared__ ushort_t As[2][2][128 * 32];   // [buf][product]
    __shared__ ushort_t Bs[2][128 * 32];

    int tid = threadIdx.x, lane = tid & 63, wid = tid >> 6;
    int wr = wid >> 1, wc = wid & 1;
    int n0 = blockIdx.x * 128, i0 = blockIdx.y * 128, z = blockIdx.z;
    int kbase = z * 384;
    ushort_t* Hout = hpart + (size_t)z * 524288;

    f32x4 acc[4][4] = {};

    // chunk c: row=c>>2, slot=c&3; source pre-swizzled by slot^((row>>1)&3)
    #define STAGE(buf, koff)                                                                 \
    {                                                                                        \
        _Pragma("unroll")                                                                    \
        for (int r = 0; r < 2; ++r) {                                                        \
            int c = r * 256 + tid; int row = c >> 2, slot = c & 3;                           \
            int so = (koff) + ((slot ^ ((row >> 1) & 3)) * 8);                               \
            GLOAD16(qhi + (size_t)(i0 + row) * 6144 + so, &As[buf][0][c * 8]);               \
            GLOAD16(qlo + (size_t)(i0 + row) * 6144 + so, &As[buf][1][c * 8]);               \
            GLOAD16(ghi + (size_t)(n0 + row) * 6144 + so, &Bs[buf][c * 8]);                  \
        }                                                                                    \
    }

    STAGE(0, kbase);
    int cur = 0;
    for (int s = 0; s < 12; ++s) {
        __syncthreads();
        if (s + 1 < 12) STAGE(cur ^ 1, kbase + (s + 1) * 32);
        bf16x8 b[4], ah[4], al[4];
        #pragma unroll
        for (int ni = 0; ni < 4; ++ni) {
            int row = wc * 64 + ni * 16 + (lane & 15);
            int slot = (lane >> 4) ^ ((row >> 1) & 3);
            b[ni] = *(const bf16x8*)&Bs[cur][row * 32 + slot * 8];
        }
        #pragma unroll
        for (int mi = 0; mi < 4; ++mi) {
            int row = wr * 64 + mi * 16 + (lane & 15);
            int slot = (lane >> 4) ^ ((row >> 1) & 3);
            ah[mi] = *(const bf16x8*)&As[cur][0][row * 32 + slot * 8];
            al[mi] = *(const bf16x8*)&As[cur][1][row * 32 + slot * 8];
        }
        #pragma unroll
        for (int mi = 0; mi < 4; ++mi)
            #pragma unroll
            for (int ni = 0; ni < 4; ++ni) {
                acc[mi][ni] = __builtin_amdgcn_mfma_f32_16x16x32_bf16(ah[mi], b[ni], acc[mi][ni], 0, 0, 0);
                acc[mi][ni] = __builtin_amdgcn_mfma_f32_16x16x32_bf16(al[mi], b[ni], acc[mi][ni], 0, 0, 0);
            }
        cur ^= 1;
    }
    #undef STAGE

    int r4 = (lane >> 4) * 4, cn = lane & 15;
    #pragma unroll
    for (int mi = 0; mi < 4; ++mi)
        #pragma unroll
        for (int ni = 0; ni < 4; ++ni)
            #pragma unroll
            for (int r = 0; r < 4; ++r) {
                int row = i0 + wr * 64 + mi * 16 + r4 + r;
                int col = n0 + wc * 64 + ni * 16 + cn;
                Hout[(size_t)row * 2048 + col] = bf16bits(acc[mi][ni][r]);
            }
}

// ---------------------------------------------------------------- K4: z-reduce + score + softmax (+ bf16 att)
typedef ushort_t ushort8 __attribute__((ext_vector_type(8)));
__global__ __launch_bounds__(256) void score_softmax_kernel(
    const ushort_t* __restrict__ hpart, const float* __restrict__ b1g,
    const float* __restrict__ w2g, const float* __restrict__ b2g,
    float* __restrict__ att, ushort_t* __restrict__ attbf)
{
    int i = blockIdx.x, j = threadIdx.x;
    float hm[8];
    #pragma unroll
    for (int m = 0; m < 8; ++m) hm[m] = b1g[m];
    #pragma unroll 4
    for (int z = 0; z < 16; ++z) {
        ushort8 u = *(const ushort8*)(hpart + (size_t)z * 524288 + (size_t)i * 2048 + j * 8);
        #pragma unroll
        for (int m = 0; m < 8; ++m) hm[m] += bf2f(u[m]);
    }
    float sv = b2g[0];
    #pragma unroll
    for (int m = 0; m < 8; ++m) sv += fmaxf(hm[m], 0.f) * w2g[m];

    __shared__ float wred[4], wred2[4];
    float mx = sv;
    #pragma unroll
    for (int off = 32; off > 0; off >>= 1) mx = fmaxf(mx, __shfl_down(mx, off, 64));
    if ((j & 63) == 0) wred[j >> 6] = mx;
    __syncthreads();
    mx = fmaxf(fmaxf(wred[0], wred[1]), fmaxf(wred[2], wred[3]));

    float e = expf(sv - mx);
    float sum = e;
    #pragma unroll
    for (int off = 32; off > 0; off >>= 1) sum += __shfl_down(sum, off, 64);
    if ((j & 63) == 0) wred2[j >> 6] = sum;
    __syncthreads();
    sum = wred2[0] + wred2[1] + wred2[2] + wred2[3];

    float pv = e / sum;
    att[(size_t)i * 256 + j] = pv;
    attbf[(size_t)i * 256 + j] = bf16bits(pv);
}

// ---------------------------------------------------------------- K5: b = att @ v via MFMA
__global__ __launch_bounds__(256) void av_kernel(
    const ushort_t* __restrict__ attbf, const ushort_t* __restrict__ vt,
    float* __restrict__ bmat)
{
    __shared__ ushort_t As[2][128 * 64];
    __shared__ ushort_t Bs[2][128 * 64];

    int tid = threadIdx.x, lane = tid & 63, wid = tid >> 6;
    int wr = wid >> 1, wc = wid & 1;
    int n0 = blockIdx.x * 128, i0 = blockIdx.y * 128;

    f32x4 acc[4][4] = {};

    #define STAGEAV(buf, koff)                                                              \
    {                                                                                       \
        _Pragma("unroll")                                                                   \
        for (int r = 0; r < 4; ++r) {                                                       \
            int c = r * 256 + tid; int row = c >> 3, slot = c & 7;                          \
            GLOAD16(attbf + (size_t)(i0 + row) * 256 + (koff) + ((slot ^ (row & 7)) * 8),   \
                    &As[buf][c * 8]);                                                       \
        }                                                                                   \
        _Pragma("unroll")                                                                   \
        for (int r = 0; r < 4; ++r) {                                                       \
            int c = r * 256 + tid; int row = c >> 3, slot = c & 7;                          \
            GLOAD16(vt + (size_t)(n0 + row) * 256 + (koff) + ((slot ^ (row & 7)) * 8),      \
                    &Bs[buf][c * 8]);                                                       \
        }                                                                                   \
    }

    int cur = 0;
    STAGEAV(0, 0);
    for (int s = 0; s < 4; ++s) {
        __syncthreads();
        if (s < 3) STAGEAV(cur ^ 1, (s + 1) * 64);
        #pragma unroll
        for (int kh = 0; kh < 2; ++kh) {
            bf16x8 a[4], b[4];
            #pragma unroll
            for (int mi = 0; mi < 4; ++mi) {
                int row = wr * 64 + mi * 16 + (lane & 15);
                int slot = (kh * 4 + (lane >> 4)) ^ (row & 7);
                a[mi] = *(const bf16x8*)&As[cur][row * 64 + slot * 8];
            }
            #pragma unroll
            for (int ni = 0; ni < 4; ++ni) {
                int row = wc * 64 + ni * 16 + (lane & 15);
                int slot = (kh * 4 + (lane >> 4)) ^ (row & 7);
                b[ni] = *(const bf16x8*)&Bs[cur][row * 64 + slot * 8];
            }
            #pragma unroll
            for (int mi = 0; mi < 4; ++mi)
                #pragma unroll
                for (int ni = 0; ni < 4; ++ni)
                    acc[mi][ni] = __builtin_amdgcn_mfma_f32_16x16x32_bf16(a[mi], b[ni], acc[mi][ni], 0, 0, 0);
        }
        cur ^= 1;
    }
    #undef STAGEAV

    int r4 = (lane >> 4) * 4, cn = lane & 15;
    #pragma unroll
    for (int mi = 0; mi < 4; ++mi)
        #pragma unroll
        for (int ni = 0; ni < 4; ++ni) {
            int c = n0 + wc * 64 + ni * 16 + cn;
            int kk = c / 768, rem = c - kk * 768;
            int t = rem >> 6, d = rem & 63;
            #pragma unroll
            for (int r = 0; r < 4; ++r) {
                int row = i0 + wr * 64 + mi * 16 + r4 + r;
                bmat[((size_t)row * 12 + t) * 512 + kk * 64 + d] = acc[mi][ni][r];
            }
        }
}

// ---------------------------------------------------------------- K6: y = relu(b@w3T+b3)@w4T+b4
__global__ __launch_bounds__(256) void out_kernel(
    const float* __restrict__ bmat, const float* __restrict__ w3t, const float* __restrict__ b3,
    const float* __restrict__ w4t, const float* __restrict__ b4, float* __restrict__ yout)
{
    int rb = blockIdx.x * 16;     // rows (i*12+t)
    int tid = threadIdx.x;
    __shared__ float rows[16 * 512];
    __shared__ float y1s[16 * 64];
    const float4* src = (const float4*)(bmat + (size_t)rb * 512);
    #pragma unroll
    for (int r = 0; r < 8; ++r) ((float4*)rows)[tid + r * 256] = src[tid + r * 256];
    __syncthreads();

    int dout = tid & 63, rg = tid >> 6;
    float acc[4];
    float b3v = b3[dout];
    #pragma unroll
    for (int jj = 0; jj < 4; ++jj) acc[jj] = b3v;
    for (int c4 = 0; c4 < 128; ++c4) {
        float w0 = w3t[(c4 * 4 + 0) * 64 + dout];
        float w1v = w3t[(c4 * 4 + 1) * 64 + dout];
        float w2v = w3t[(c4 * 4 + 2) * 64 + dout];
        float w3v = w3t[(c4 * 4 + 3) * 64 + dout];
        #pragma unroll
        for (int jj = 0; jj < 4; ++jj) {
            float4 rv = *(const float4*)&rows[(rg * 4 + jj) * 512 + c4 * 4];
            acc[jj] += rv.x * w0 + rv.y * w1v + rv.z * w2v + rv.w * w3v;
        }
    }
    #pragma unroll
    for (int jj = 0; jj < 4; ++jj) y1s[(rg * 4 + jj) * 64 + dout] = fmaxf(acc[jj], 0.f);
    __syncthreads();

    int f = tid & 31, rh = tid >> 5;
    #pragma unroll
    for (int rr = 0; rr < 2; ++rr) {
        int r = rh * 2 + rr;
        float a2 = b4[f];
        #pragma unroll
        for (int dd = 0; dd < 64; ++dd) a2 += y1s[r * 64 + dd] * w4t[dd * 32 + f];
        yout[(size_t)(rb + r) * 32 + f] = a2;
    }
}

// ---------------------------------------------------------------- launch
extern "C" void kernel_launch(void* const* d_in, const int* in_sizes, int n_in,
                              void* d_out, int out_size, void* d_ws, size_t ws_size,
                              hipStream_t stream) {
    (void)in_sizes; (void)n_in; (void)out_size; (void)ws_size;
    const float* x  = (const float*)d_in[0];
    const float* Wq = (const float*)d_in[1];
    const float* Wk = (const float*)d_in[2];
    const float* Wv = (const float*)d_in[3];
    const float* bq = (const float*)d_in[4];
    const float* bk = (const float*)d_in[5];
    const float* bv = (const float*)d_in[6];
    const float* w1 = (const float*)d_in[7];
    const float* b1 = (const float*)d_in[8];
    const float* w2 = (const float*)d_in[9];
    const float* b2 = (const float*)d_in[10];
    const float* w3 = (const float*)d_in[11];
    const float* b3 = (const float*)d_in[12];
    const float* w4 = (const float*)d_in[13];
    const float* b4 = (const float*)d_in[14];

    float* ws = (float*)d_ws;
    // hpart (bf16, 16z x 2048 x 256 = 8.39M ushorts = 4,194,304 float-slots) overlaps kbuf+vbuf
    float*    kbuf  = ws;                                // [0, 1572864)
    float*    vbuf  = ws + 1572864;                      // [1572864, 3145728)
    ushort_t* hpart = (ushort_t*)ws;                     // [0, 4194304) float-slots
    size_t    off   = 4194304;
    ushort_t* qhi   = (ushort_t*)(ws + off);             // 1,572,864 ushorts
    ushort_t* qlo   = (ushort_t*)(ws + off + 786432);
    ushort_t* ghi   = (ushort_t*)(ws + off + 1572864);   // 12,582,912 ushorts
    ushort_t* vt    = (ushort_t*)(ws + off + 7864320);   // 1,572,864 ushorts
    ushort_t* attbf = (ushort_t*)(ws + off + 8650752);   // 65,536 ushorts
    float*    w3t   = ws + off + 8683520;                // 32,768
    float*    w4t   = ws + off + 8716288;                // 2,048
    float*    bmat  = (float*)ghi;                       // reuse (dead after hgemm)

    float* yout = (float*)d_out;              // 98304
    float* att  = (float*)d_out + 98304;      // 65536

    qkv_kernel<<<2048, 256, 0, stream>>>(x, Wq, Wk, Wv, bq, bk, bv, qhi, qlo, kbuf, vbuf);
    gbuild_kernel<<<609, 256, 0, stream>>>(kbuf, w1, vbuf, w3, w4, ghi, vt, w3t, w4t);
    hgemm_kernel<<<dim3(16, 2, 16), 256, 0, stream>>>(qhi, qlo, ghi, hpart);
    score_softmax_kernel<<<256, 256, 0, stream>>>(hpart, b1, w2, b2, att, attbf);
    av_kernel<<<dim3(48, 2), 256, 0, stream>>>(attbf, vt, bmat);
    out_kernel<<<192, 256, 0, stream>>>(bmat, w3t, b3, w4t, b4, yout);
}

// Round 5
// 86.640 us; speedup vs baseline: 4.1682x; 1.3260x over previous
//
#include <hip/hip_runtime.h>
#include <hip/hip_bf16.h>

// N=256, T=12, F=32, T_dim=8, D=64;  c-index: c = kk*768 + t*64 + d  (size 6144)
typedef unsigned short ushort_t;
typedef __bf16 bf16x8 __attribute__((ext_vector_type(8)));
typedef float f32x4 __attribute__((ext_vector_type(4)));
typedef ushort_t ushort8 __attribute__((ext_vector_type(8)));

#define GLOAD16(gp, lp) \
    __builtin_amdgcn_global_load_lds((const __attribute__((address_space(1))) void*)(gp), \
                                     (__attribute__((address_space(3))) void*)(lp), 16, 0, 0)

__device__ __forceinline__ ushort_t bf16bits(float x) {
    __hip_bfloat16 h = __float2bfloat16(x);
    return *(ushort_t*)&h;
}
__device__ __forceinline__ float bf2f(ushort_t u) {
    unsigned v = (unsigned)u << 16;
    float f;
    __builtin_memcpy(&f, &v, 4);
    return f;
}

// ---------------------------------------------------------------- K1: QKV projection (+ Q split hi/lo scaled 0.125)
__global__ __launch_bounds__(256) void qkv_kernel(
    const float* __restrict__ x,
    const float* __restrict__ Wq, const float* __restrict__ Wk, const float* __restrict__ Wv,
    const float* __restrict__ bq, const float* __restrict__ bk, const float* __restrict__ bv,
    ushort_t* __restrict__ qhi, ushort_t* __restrict__ qlo,
    float* __restrict__ k, float* __restrict__ v)
{
    int b = blockIdx.x;          // 0..2047
    int n = b >> 3;
    __shared__ float xs[384];
    int tid = threadIdx.x;
    if (tid < 96) ((float4*)xs)[tid] = ((const float4*)(x + n * 384))[tid];
    __syncthreads();

    int d = tid & 63, tg = tid >> 6;
    const float* wqb = Wq + (size_t)b * 2048 + d;
    const float* wkb = Wk + (size_t)b * 2048 + d;
    const float* wvb = Wv + (size_t)b * 2048 + d;
    float aq[3] = {0.f,0.f,0.f}, ak[3] = {0.f,0.f,0.f}, av[3] = {0.f,0.f,0.f};
    #pragma unroll 8
    for (int f = 0; f < 32; ++f) {
        float wq = wqb[f * 64], wk = wkb[f * 64], wv = wvb[f * 64];
        #pragma unroll
        for (int tt = 0; tt < 3; ++tt) {
            float xv = xs[(tg + tt * 4) * 32 + f];
            aq[tt] += xv * wq; ak[tt] += xv * wk; av[tt] += xv * wv;
        }
    }
    float bqv = bq[b * 64 + d], bkv = bk[b * 64 + d], bvv = bv[b * 64 + d];
    #pragma unroll
    for (int tt = 0; tt < 3; ++tt) {
        int t = tg + tt * 4;
        size_t o = ((size_t)b * 12 + t) * 64 + d;
        float qs = 0.125f * (aq[tt] + bqv);
        __hip_bfloat16 qh = __float2bfloat16(qs);
        qhi[o] = *(ushort_t*)&qh;
        qlo[o] = bf16bits(qs - __bfloat162float(qh));
        k[o] = ak[tt] + bkv;
        v[o] = av[tt] + bvv;
    }
}

// ---------------------------------------------------------------- K2: G build (0..2047) + v transpose (2048..2431) + w prep (2432..2447)
// G[(j*8+m)][kk*768+t*64+d] = sum_s w1[m][kk*144+t*12+s] * k[j*8+kk][s][d], single bf16
__global__ __launch_bounds__(256) void gbuild_kernel(
    const float* __restrict__ kg, const float* __restrict__ w1,
    const float* __restrict__ v, const float* __restrict__ w3, const float* __restrict__ w4,
    ushort_t* __restrict__ ghi, ushort_t* __restrict__ vt,
    float* __restrict__ w3t, float* __restrict__ w4t)
{
    __shared__ alignas(16) char sbuf[8448];   // union: ks 3072 B | ts 8256 B
    int bx = blockIdx.x, tid = threadIdx.x;

    if (bx < 2048) {
        // one block per (j, kk)
        int j = bx >> 3, kk = bx & 7;
        float* ks = (float*)sbuf;            // k[j*8+kk]: [s][d] 768 floats
        if (tid < 192)
            ((float4*)ks)[tid] = ((const float4*)(kg + ((size_t)j * 8 + kk) * 768))[tid];
        __syncthreads();

        #pragma unroll
        for (int r = 0; r < 3; ++r) {
            int e = r * 256 + tid;               // 0..767 -> (m, t, d8)
            int m = e / 96, rem = e - m * 96;
            int t = rem >> 3, d8 = rem & 7;
            const float* w1p = w1 + m * 1152 + kk * 144 + t * 12;
            float acc[8] = {0.f,0.f,0.f,0.f,0.f,0.f,0.f,0.f};
            #pragma unroll
            for (int s = 0; s < 12; ++s) {
                float wv = w1p[s];
                const float4* kp = (const float4*)(ks + s * 64 + d8 * 8);
                float4 k0 = kp[0], k1 = kp[1];
                acc[0] += wv * k0.x; acc[1] += wv * k0.y;
                acc[2] += wv * k0.z; acc[3] += wv * k0.w;
                acc[4] += wv * k1.x; acc[5] += wv * k1.y;
                acc[6] += wv * k1.z; acc[7] += wv * k1.w;
            }
            ushort8 u;
            #pragma unroll
            for (int dd = 0; dd < 8; ++dd) u[dd] = bf16bits(acc[dd]);
            *(ushort8*)(ghi + ((size_t)j * 8 + m) * 6144 + kk * 768 + t * 64 + d8 * 8) = u;
        }
        return;
    }

    if (bx < 2432) {
        // v (fp32 [j][c]) -> bf16 vt[c][j]; 16 c-cols x 256 j per block
        ushort_t (*ts)[258] = (ushort_t(*)[258])sbuf;
        int c0 = (bx - 2048) * 16;
        int cc = tid & 15, jg = tid >> 4;
        #pragma unroll 4
        for (int jj = 0; jj < 16; ++jj) {
            int j = jg * 16 + jj;
            ts[cc][j] = bf16bits(v[(size_t)j * 6144 + c0 + cc]);
        }
        __syncthreads();
        #pragma unroll
        for (int c = 0; c < 16; ++c)
            vt[(size_t)(c0 + c) * 256 + tid] = ts[c][tid];
        return;
    }

    // w3 (64 dout x 512 c3, c3=d*8+kk) -> w3t[cb*64+dout], cb = kk*64+d ; 16 blocks
    int wb = bx - 2432;
    #pragma unroll
    for (int r = 0; r < 8; ++r) {
        int e = wb * 2048 + r * 256 + tid;
        int dout = e >> 9, c3 = e & 511;
        int cb = ((c3 & 7) << 6) | (c3 >> 3);
        w3t[cb * 64 + dout] = w3[e];
    }
    if (wb == 0) {
        #pragma unroll
        for (int r = 0; r < 8; ++r) {
            int e = r * 256 + tid; int f = e >> 6, d = e & 63;
            w4t[d * 32 + f] = w4[e];
        }
    }
}

// ---------------------------------------------------------------- K3: H GEMM
// H[i][(j,m)] = (Qhi+Qlo) . G ; block 128x128, 4 waves 64x64, BK=32, nz=16 K-split
__global__ __launch_bounds__(256, 2) void hgemm_kernel(
    const ushort_t* __restrict__ qhi, const ushort_t* __restrict__ qlo,
    const ushort_t* __restrict__ ghi, ushort_t* __restrict__ hpart)
{
    __shared__ ushort_t As[2][2][128 * 32];   // [buf][product]
    __shared__ ushort_t Bs[2][128 * 32];

    int tid = threadIdx.x, lane = tid & 63, wid = tid >> 6;
    int wr = wid >> 1, wc = wid & 1;
    int n0 = blockIdx.x * 128, i0 = blockIdx.y * 128, z = blockIdx.z;
    int kbase = z * 384;
    ushort_t* Hout = hpart + (size_t)z * 524288;

    f32x4 acc[4][4] = {};

    #define STAGE(buf, koff)                                                                 \
    {                                                                                        \
        _Pragma("unroll")                                                                    \
        for (int r = 0; r < 2; ++r) {                                                        \
            int c = r * 256 + tid; int row = c >> 2, slot = c & 3;                           \
            int so = (koff) + ((slot ^ ((row >> 1) & 3)) * 8);                               \
            GLOAD16(qhi + (size_t)(i0 + row) * 6144 + so, &As[buf][0][c * 8]);               \
            GLOAD16(qlo + (size_t)(i0 + row) * 6144 + so, &As[buf][1][c * 8]);               \
            GLOAD16(ghi + (size_t)(n0 + row) * 6144 + so, &Bs[buf][c * 8]);                  \
        }                                                                                    \
    }

    STAGE(0, kbase);
    int cur = 0;
    for (int s = 0; s < 12; ++s) {
        __syncthreads();
        if (s + 1 < 12) STAGE(cur ^ 1, kbase + (s + 1) * 32);
        bf16x8 b[4], ah[4], al[4];
        #pragma unroll
        for (int ni = 0; ni < 4; ++ni) {
            int row = wc * 64 + ni * 16 + (lane & 15);
            int slot = (lane >> 4) ^ ((row >> 1) & 3);
            b[ni] = *(const bf16x8*)&Bs[cur][row * 32 + slot * 8];
        }
        #pragma unroll
        for (int mi = 0; mi < 4; ++mi) {
            int row = wr * 64 + mi * 16 + (lane & 15);
            int slot = (lane >> 4) ^ ((row >> 1) & 3);
            ah[mi] = *(const bf16x8*)&As[cur][0][row * 32 + slot * 8];
            al[mi] = *(const bf16x8*)&As[cur][1][row * 32 + slot * 8];
        }
        #pragma unroll
        for (int mi = 0; mi < 4; ++mi)
            #pragma unroll
            for (int ni = 0; ni < 4; ++ni) {
                acc[mi][ni] = __builtin_amdgcn_mfma_f32_16x16x32_bf16(ah[mi], b[ni], acc[mi][ni], 0, 0, 0);
                acc[mi][ni] = __builtin_amdgcn_mfma_f32_16x16x32_bf16(al[mi], b[ni], acc[mi][ni], 0, 0, 0);
            }
        cur ^= 1;
    }
    #undef STAGE

    int r4 = (lane >> 4) * 4, cn = lane & 15;
    #pragma unroll
    for (int mi = 0; mi < 4; ++mi)
        #pragma unroll
        for (int ni = 0; ni < 4; ++ni)
            #pragma unroll
            for (int r = 0; r < 4; ++r) {
                int row = i0 + wr * 64 + mi * 16 + r4 + r;
                int col = n0 + wc * 64 + ni * 16 + cn;
                Hout[(size_t)row * 2048 + col] = bf16bits(acc[mi][ni][r]);
            }
}

// ---------------------------------------------------------------- K4: z-reduce + score + softmax (+ bf16 att)
__global__ __launch_bounds__(256) void score_softmax_kernel(
    const ushort_t* __restrict__ hpart, const float* __restrict__ b1g,
    const float* __restrict__ w2g, const float* __restrict__ b2g,
    float* __restrict__ att, ushort_t* __restrict__ attbf)
{
    int i = blockIdx.x, j = threadIdx.x;
    float hm[8];
    #pragma unroll
    for (int m = 0; m < 8; ++m) hm[m] = b1g[m];
    #pragma unroll 4
    for (int z = 0; z < 16; ++z) {
        ushort8 u = *(const ushort8*)(hpart + (size_t)z * 524288 + (size_t)i * 2048 + j * 8);
        #pragma unroll
        for (int m = 0; m < 8; ++m) hm[m] += bf2f(u[m]);
    }
    float sv = b2g[0];
    #pragma unroll
    for (int m = 0; m < 8; ++m) sv += fmaxf(hm[m], 0.f) * w2g[m];

    __shared__ float wred[4], wred2[4];
    float mx = sv;
    #pragma unroll
    for (int off = 32; off > 0; off >>= 1) mx = fmaxf(mx, __shfl_down(mx, off, 64));
    if ((j & 63) == 0) wred[j >> 6] = mx;
    __syncthreads();
    mx = fmaxf(fmaxf(wred[0], wred[1]), fmaxf(wred[2], wred[3]));

    float e = expf(sv - mx);
    float sum = e;
    #pragma unroll
    for (int off = 32; off > 0; off >>= 1) sum += __shfl_down(sum, off, 64);
    if ((j & 63) == 0) wred2[j >> 6] = sum;
    __syncthreads();
    sum = wred2[0] + wred2[1] + wred2[2] + wred2[3];

    float pv = e / sum;
    att[(size_t)i * 256 + j] = pv;
    attbf[(size_t)i * 256 + j] = bf16bits(pv);
}

// ---------------------------------------------------------------- K5: b = att @ v via MFMA
__global__ __launch_bounds__(256) void av_kernel(
    const ushort_t* __restrict__ attbf, const ushort_t* __restrict__ vt,
    float* __restrict__ bmat)
{
    __shared__ ushort_t As[2][128 * 64];
    __shared__ ushort_t Bs[2][128 * 64];

    int tid = threadIdx.x, lane = tid & 63, wid = tid >> 6;
    int wr = wid >> 1, wc = wid & 1;
    int n0 = blockIdx.x * 128, i0 = blockIdx.y * 128;

    f32x4 acc[4][4] = {};

    #define STAGEAV(buf, koff)                                                              \
    {                                                                                       \
        _Pragma("unroll")                                                                   \
        for (int r = 0; r < 4; ++r) {                                                       \
            int c = r * 256 + tid; int row = c >> 3, slot = c & 7;                          \
            GLOAD16(attbf + (size_t)(i0 + row) * 256 + (koff) + ((slot ^ (row & 7)) * 8),   \
                    &As[buf][c * 8]);                                                       \
        }                                                                                   \
        _Pragma("unroll")                                                                   \
        for (int r = 0; r < 4; ++r) {                                                       \
            int c = r * 256 + tid; int row = c >> 3, slot = c & 7;                          \
            GLOAD16(vt + (size_t)(n0 + row) * 256 + (koff) + ((slot ^ (row & 7)) * 8),      \
                    &Bs[buf][c * 8]);                                                       \
        }                                                                                   \
    }

    int cur = 0;
    STAGEAV(0, 0);
    for (int s = 0; s < 4; ++s) {
        __syncthreads();
        if (s < 3) STAGEAV(cur ^ 1, (s + 1) * 64);
        #pragma unroll
        for (int kh = 0; kh < 2; ++kh) {
            bf16x8 a[4], b[4];
            #pragma unroll
            for (int mi = 0; mi < 4; ++mi) {
                int row = wr * 64 + mi * 16 + (lane & 15);
                int slot = (kh * 4 + (lane >> 4)) ^ (row & 7);
                a[mi] = *(const bf16x8*)&As[cur][row * 64 + slot * 8];
            }
            #pragma unroll
            for (int ni = 0; ni < 4; ++ni) {
                int row = wc * 64 + ni * 16 + (lane & 15);
                int slot = (kh * 4 + (lane >> 4)) ^ (row & 7);
                b[ni] = *(const bf16x8*)&Bs[cur][row * 64 + slot * 8];
            }
            #pragma unroll
            for (int mi = 0; mi < 4; ++mi)
                #pragma unroll
                for (int ni = 0; ni < 4; ++ni)
                    acc[mi][ni] = __builtin_amdgcn_mfma_f32_16x16x32_bf16(a[mi], b[ni], acc[mi][ni], 0, 0, 0);
        }
        cur ^= 1;
    }
    #undef STAGEAV

    int r4 = (lane >> 4) * 4, cn = lane & 15;
    #pragma unroll
    for (int mi = 0; mi < 4; ++mi)
        #pragma unroll
        for (int ni = 0; ni < 4; ++ni) {
            int c = n0 + wc * 64 + ni * 16 + cn;
            int kk = c / 768, rem = c - kk * 768;
            int t = rem >> 6, d = rem & 63;
            #pragma unroll
            for (int r = 0; r < 4; ++r) {
                int row = i0 + wr * 64 + mi * 16 + r4 + r;
                bmat[((size_t)row * 12 + t) * 512 + kk * 64 + d] = acc[mi][ni][r];
            }
        }
}

// ---------------------------------------------------------------- K6: y = relu(b@w3T+b3)@w4T+b4
__global__ __launch_bounds__(256) void out_kernel(
    const float* __restrict__ bmat, const float* __restrict__ w3t, const float* __restrict__ b3,
    const float* __restrict__ w4t, const float* __restrict__ b4, float* __restrict__ yout)
{
    int rb = blockIdx.x * 16;     // rows (i*12+t)
    int tid = threadIdx.x;
    __shared__ float rows[16 * 512];
    __shared__ float y1s[16 * 64];
    const float4* src = (const float4*)(bmat + (size_t)rb * 512);
    #pragma unroll
    for (int r = 0; r < 8; ++r) ((float4*)rows)[tid + r * 256] = src[tid + r * 256];
    __syncthreads();

    int dout = tid & 63, rg = tid >> 6;
    float acc[4];
    float b3v = b3[dout];
    #pragma unroll
    for (int jj = 0; jj < 4; ++jj) acc[jj] = b3v;
    for (int c4 = 0; c4 < 128; ++c4) {
        float w0 = w3t[(c4 * 4 + 0) * 64 + dout];
        float w1v = w3t[(c4 * 4 + 1) * 64 + dout];
        float w2v = w3t[(c4 * 4 + 2) * 64 + dout];
        float w3v = w3t[(c4 * 4 + 3) * 64 + dout];
        #pragma unroll
        for (int jj = 0; jj < 4; ++jj) {
            float4 rv = *(const float4*)&rows[(rg * 4 + jj) * 512 + c4 * 4];
            acc[jj] += rv.x * w0 + rv.y * w1v + rv.z * w2v + rv.w * w3v;
        }
    }
    #pragma unroll
    for (int jj = 0; jj < 4; ++jj) y1s[(rg * 4 + jj) * 64 + dout] = fmaxf(acc[jj], 0.f);
    __syncthreads();

    int f = tid & 31, rh = tid >> 5;
    #pragma unroll
    for (int rr = 0; rr < 2; ++rr) {
        int r = rh * 2 + rr;
        float a2 = b4[f];
        #pragma unroll
        for (int dd = 0; dd < 64; ++dd) a2 += y1s[r * 64 + dd] * w4t[dd * 32 + f];
        yout[(size_t)(rb + r) * 32 + f] = a2;
    }
}

// ---------------------------------------------------------------- launch
extern "C" void kernel_launch(void* const* d_in, const int* in_sizes, int n_in,
                              void* d_out, int out_size, void* d_ws, size_t ws_size,
                              hipStream_t stream) {
    (void)in_sizes; (void)n_in; (void)out_size; (void)ws_size;
    const float* x  = (const float*)d_in[0];
    const float* Wq = (const float*)d_in[1];
    const float* Wk = (const float*)d_in[2];
    const float* Wv = (const float*)d_in[3];
    const float* bq = (const float*)d_in[4];
    const float* bk = (const float*)d_in[5];
    const float* bv = (const float*)d_in[6];
    const float* w1 = (const float*)d_in[7];
    const float* b1 = (const float*)d_in[8];
    const float* w2 = (const float*)d_in[9];
    const float* b2 = (const float*)d_in[10];
    const float* w3 = (const float*)d_in[11];
    const float* b3 = (const float*)d_in[12];
    const float* w4 = (const float*)d_in[13];
    const float* b4 = (const float*)d_in[14];

    float* ws = (float*)d_ws;
    // hpart (bf16, 16z x 2048 x 256 = 8.39M ushorts = 4,194,304 float-slots) overlaps kbuf+vbuf
    float*    kbuf  = ws;                                // [0, 1572864)
    float*    vbuf  = ws + 1572864;                      // [1572864, 3145728)
    ushort_t* hpart = (ushort_t*)ws;                     // [0, 4194304) float-slots
    size_t    off   = 4194304;
    ushort_t* qhi   = (ushort_t*)(ws + off);             // 1,572,864 ushorts
    ushort_t* qlo   = (ushort_t*)(ws + off + 786432);
    ushort_t* ghi   = (ushort_t*)(ws + off + 1572864);   // 12,582,912 ushorts
    ushort_t* vt    = (ushort_t*)(ws + off + 7864320);   // 1,572,864 ushorts
    ushort_t* attbf = (ushort_t*)(ws + off + 8650752);   // 65,536 ushorts
    float*    w3t   = ws + off + 8683520;                // 32,768
    float*    w4t   = ws + off + 8716288;                // 2,048
    float*    bmat  = (float*)ghi;                       // reuse (dead after hgemm)

    float* yout = (float*)d_out;              // 98304
    float* att  = (float*)d_out + 98304;      // 65536

    qkv_kernel<<<2048, 256, 0, stream>>>(x, Wq, Wk, Wv, bq, bk, bv, qhi, qlo, kbuf, vbuf);
    gbuild_kernel<<<2448, 256, 0, stream>>>(kbuf, w1, vbuf, w3, w4, ghi, vt, w3t, w4t);
    hgemm_kernel<<<dim3(16, 2, 16), 256, 0, stream>>>(qhi, qlo, ghi, hpart);
    score_softmax_kernel<<<256, 256, 0, stream>>>(hpart, b1, w2, b2, att, attbf);
    av_kernel<<<dim3(48, 2), 256, 0, stream>>>(attbf, vt, bmat);
    out_kernel<<<192, 256, 0, stream>>>(bmat, w3t, b3, w4t, b4, yout);
}

// Round 6
// 83.136 us; speedup vs baseline: 4.3439x; 1.0422x over previous
//
#include <hip/hip_runtime.h>
#include <hip/hip_bf16.h>

// N=256, T=12, F=32, T_dim=8, D=64;  c-index: c = kk*768 + t*64 + d  (size 6144)
typedef unsigned short ushort_t;
typedef __bf16 bf16x8 __attribute__((ext_vector_type(8)));
typedef float f32x4 __attribute__((ext_vector_type(4)));
typedef ushort_t ushort8 __attribute__((ext_vector_type(8)));

#define GLOAD16(gp, lp) \
    __builtin_amdgcn_global_load_lds((const __attribute__((address_space(1))) void*)(gp), \
                                     (__attribute__((address_space(3))) void*)(lp), 16, 0, 0)

__device__ __forceinline__ ushort_t bf16bits(float x) {
    __hip_bfloat16 h = __float2bfloat16(x);
    return *(ushort_t*)&h;
}
__device__ __forceinline__ float bf2f(ushort_t u) {
    unsigned v = (unsigned)u << 16;
    float f;
    __builtin_memcpy(&f, &v, 4);
    return f;
}

// ---------------------------------------------------------------- K1: fused QKV projection + G build
// block b = j*8+kk owns k-row b: computes q(bf16), v(bf16), and G[(j*8+m)][kk*768+t*64+d]
__global__ __launch_bounds__(256) void qkvg_kernel(
    const float* __restrict__ x,
    const float* __restrict__ Wq, const float* __restrict__ Wk, const float* __restrict__ Wv,
    const float* __restrict__ bq, const float* __restrict__ bk, const float* __restrict__ bv,
    const float* __restrict__ w1,
    ushort_t* __restrict__ qhi, ushort_t* __restrict__ vbf, ushort_t* __restrict__ ghi)
{
    int b = blockIdx.x;          // 0..2047
    int j = b >> 3, kk = b & 7;
    __shared__ float xs[384];
    __shared__ float ks[768];     // k[b]: [t][d]
    __shared__ float w1s[1152];   // w1[m][kk*144 + z] -> w1s[m*144+z]
    int tid = threadIdx.x;
    if (tid < 96) ((float4*)xs)[tid] = ((const float4*)(x + j * 384))[tid];
    for (int e = tid; e < 1152; e += 256)
        w1s[e] = w1[(e / 144) * 1152 + kk * 144 + (e % 144)];
    __syncthreads();

    int d = tid & 63, tg = tid >> 6;
    const float* wqb = Wq + (size_t)b * 2048 + d;
    const float* wkb = Wk + (size_t)b * 2048 + d;
    const float* wvb = Wv + (size_t)b * 2048 + d;
    float aq[3] = {0.f,0.f,0.f}, ak[3] = {0.f,0.f,0.f}, av[3] = {0.f,0.f,0.f};
    #pragma unroll 8
    for (int f = 0; f < 32; ++f) {
        float wq = wqb[f * 64], wk = wkb[f * 64], wv = wvb[f * 64];
        #pragma unroll
        for (int tt = 0; tt < 3; ++tt) {
            float xv = xs[(tg + tt * 4) * 32 + f];
            aq[tt] += xv * wq; ak[tt] += xv * wk; av[tt] += xv * wv;
        }
    }
    float bqv = bq[b * 64 + d], bkv = bk[b * 64 + d], bvv = bv[b * 64 + d];
    #pragma unroll
    for (int tt = 0; tt < 3; ++tt) {
        int t = tg + tt * 4;
        size_t o = ((size_t)b * 12 + t) * 64 + d;
        qhi[o] = bf16bits(0.125f * (aq[tt] + bqv));
        float kv = ak[tt] + bkv;
        ks[t * 64 + d] = kv;
        vbf[o] = bf16bits(av[tt] + bvv);
    }
    __syncthreads();

    // G: 768 ushort8 outputs / 256 threads = 3 each
    #pragma unroll
    for (int r = 0; r < 3; ++r) {
        int e = r * 256 + tid;               // (m, t, d8)
        int m = e / 96, rem = e - m * 96;
        int t = rem >> 3, d8 = rem & 7;
        const float* w1p = w1s + m * 144 + t * 12;
        float acc[8] = {0.f,0.f,0.f,0.f,0.f,0.f,0.f,0.f};
        #pragma unroll
        for (int s = 0; s < 12; ++s) {
            float wv = w1p[s];
            const float4* kp = (const float4*)(ks + s * 64 + d8 * 8);
            float4 k0 = kp[0], k1 = kp[1];
            acc[0] += wv * k0.x; acc[1] += wv * k0.y;
            acc[2] += wv * k0.z; acc[3] += wv * k0.w;
            acc[4] += wv * k1.x; acc[5] += wv * k1.y;
            acc[6] += wv * k1.z; acc[7] += wv * k1.w;
        }
        ushort8 u;
        #pragma unroll
        for (int dd = 0; dd < 8; ++dd) u[dd] = bf16bits(acc[dd]);
        *(ushort8*)(ghi + ((size_t)j * 8 + m) * 6144 + kk * 768 + t * 64 + d8 * 8) = u;
    }
}

// ---------------------------------------------------------------- K2: prep — vt transpose (0..383) + w3t (384..399) + w4t (400)
__global__ __launch_bounds__(256) void prep_kernel(
    const ushort_t* __restrict__ vbf, const float* __restrict__ w3, const float* __restrict__ w4,
    ushort_t* __restrict__ vt, float* __restrict__ w3t, float* __restrict__ w4t)
{
    int bx = blockIdx.x, tid = threadIdx.x;
    if (bx < 384) {
        // vbf [j][6144] -> vt[c][j]; 16 c-cols x 256 j per block
        __shared__ ushort_t ts[16][264];
        int c0 = bx * 16;
        int cc = tid & 15, jg = tid >> 4;
        #pragma unroll 4
        for (int jj = 0; jj < 16; ++jj) {
            int j = jg * 16 + jj;
            ts[cc][j] = vbf[(size_t)j * 6144 + c0 + cc];
        }
        __syncthreads();
        #pragma unroll
        for (int c = 0; c < 16; ++c)
            vt[(size_t)(c0 + c) * 256 + tid] = ts[c][tid];
        return;
    }
    if (bx < 400) {
        // w3 (64 dout x 512 c3, c3=d*8+kk) -> w3t[cb*64+dout], cb = kk*64+d
        int wb = bx - 384;
        #pragma unroll
        for (int r = 0; r < 8; ++r) {
            int e = wb * 2048 + r * 256 + tid;
            int dout = e >> 9, c3 = e & 511;
            int cb = ((c3 & 7) << 6) | (c3 >> 3);
            w3t[cb * 64 + dout] = w3[e];
        }
        return;
    }
    #pragma unroll
    for (int r = 0; r < 8; ++r) {
        int e = r * 256 + tid; int f = e >> 6, dd = e & 63;
        w4t[dd * 32 + f] = w4[e];
    }
}

// ---------------------------------------------------------------- K3: H GEMM (single bf16 product)
// H[i][(j,m)] = Qhi . G ; block 128x128, 4 waves 64x64, BK=32, nz=16 K-split
// XCD-aware: z-major so each XCD's working set (~3.5 MB) fits its private L2
__global__ __launch_bounds__(256, 2) void hgemm_kernel(
    const ushort_t* __restrict__ qhi, const ushort_t* __restrict__ ghi,
    ushort_t* __restrict__ hpart)
{
    __shared__ ushort_t As[2][128 * 32];
    __shared__ ushort_t Bs[2][128 * 32];

    int tid = threadIdx.x, lane = tid & 63, wid = tid >> 6;
    int wr = wid >> 1, wc = wid & 1;

    int bid = blockIdx.x;                 // 0..511
    int xcd = bid & 7, kq = bid >> 3;     // kq 0..63
    int z = xcd + 8 * (kq >> 5);
    int rem = kq & 31;
    int n0 = (rem & 15) * 128, i0 = (rem >> 4) * 128;
    int kbase = z * 384;
    ushort_t* Hout = hpart + (size_t)z * 524288;

    f32x4 acc[4][4] = {};

    #define STAGE(buf, koff)                                                                 \
    {                                                                                        \
        _Pragma("unroll")                                                                    \
        for (int r = 0; r < 2; ++r) {                                                        \
            int c = r * 256 + tid; int row = c >> 2, slot = c & 3;                           \
            int so = (koff) + ((slot ^ ((row >> 1) & 3)) * 8);                               \
            GLOAD16(qhi + (size_t)(i0 + row) * 6144 + so, &As[buf][c * 8]);                  \
            GLOAD16(ghi + (size_t)(n0 + row) * 6144 + so, &Bs[buf][c * 8]);                  \
        }                                                                                    \
    }

    STAGE(0, kbase);
    int cur = 0;
    for (int s = 0; s < 12; ++s) {
        __syncthreads();
        if (s + 1 < 12) STAGE(cur ^ 1, kbase + (s + 1) * 32);
        bf16x8 a[4], b[4];
        #pragma unroll
        for (int ni = 0; ni < 4; ++ni) {
            int row = wc * 64 + ni * 16 + (lane & 15);
            int slot = (lane >> 4) ^ ((row >> 1) & 3);
            b[ni] = *(const bf16x8*)&Bs[cur][row * 32 + slot * 8];
        }
        #pragma unroll
        for (int mi = 0; mi < 4; ++mi) {
            int row = wr * 64 + mi * 16 + (lane & 15);
            int slot = (lane >> 4) ^ ((row >> 1) & 3);
            a[mi] = *(const bf16x8*)&As[cur][row * 32 + slot * 8];
        }
        #pragma unroll
        for (int mi = 0; mi < 4; ++mi)
            #pragma unroll
            for (int ni = 0; ni < 4; ++ni)
                acc[mi][ni] = __builtin_amdgcn_mfma_f32_16x16x32_bf16(a[mi], b[ni], acc[mi][ni], 0, 0, 0);
        cur ^= 1;
    }
    #undef STAGE

    int r4 = (lane >> 4) * 4, cn = lane & 15;
    #pragma unroll
    for (int mi = 0; mi < 4; ++mi)
        #pragma unroll
        for (int ni = 0; ni < 4; ++ni)
            #pragma unroll
            for (int r = 0; r < 4; ++r) {
                int row = i0 + wr * 64 + mi * 16 + r4 + r;
                int col = n0 + wc * 64 + ni * 16 + cn;
                Hout[(size_t)row * 2048 + col] = bf16bits(acc[mi][ni][r]);
            }
}

// ---------------------------------------------------------------- K4: z-reduce + score + softmax (+ bf16 att)
__global__ __launch_bounds__(256) void score_softmax_kernel(
    const ushort_t* __restrict__ hpart, const float* __restrict__ b1g,
    const float* __restrict__ w2g, const float* __restrict__ b2g,
    float* __restrict__ att, ushort_t* __restrict__ attbf)
{
    int i = blockIdx.x, j = threadIdx.x;
    float hm[8];
    #pragma unroll
    for (int m = 0; m < 8; ++m) hm[m] = b1g[m];
    #pragma unroll 4
    for (int z = 0; z < 16; ++z) {
        ushort8 u = *(const ushort8*)(hpart + (size_t)z * 524288 + (size_t)i * 2048 + j * 8);
        #pragma unroll
        for (int m = 0; m < 8; ++m) hm[m] += bf2f(u[m]);
    }
    float sv = b2g[0];
    #pragma unroll
    for (int m = 0; m < 8; ++m) sv += fmaxf(hm[m], 0.f) * w2g[m];

    __shared__ float wred[4], wred2[4];
    float mx = sv;
    #pragma unroll
    for (int off = 32; off > 0; off >>= 1) mx = fmaxf(mx, __shfl_down(mx, off, 64));
    if ((j & 63) == 0) wred[j >> 6] = mx;
    __syncthreads();
    mx = fmaxf(fmaxf(wred[0], wred[1]), fmaxf(wred[2], wred[3]));

    float e = expf(sv - mx);
    float sum = e;
    #pragma unroll
    for (int off = 32; off > 0; off >>= 1) sum += __shfl_down(sum, off, 64);
    if ((j & 63) == 0) wred2[j >> 6] = sum;
    __syncthreads();
    sum = wred2[0] + wred2[1] + wred2[2] + wred2[3];

    float pv = e / sum;
    att[(size_t)i * 256 + j] = pv;
    attbf[(size_t)i * 256 + j] = bf16bits(pv);
}

// ---------------------------------------------------------------- K5: b = att @ v via MFMA
__global__ __launch_bounds__(256) void av_kernel(
    const ushort_t* __restrict__ attbf, const ushort_t* __restrict__ vt,
    float* __restrict__ bmat)
{
    __shared__ ushort_t As[2][128 * 64];
    __shared__ ushort_t Bs[2][128 * 64];

    int tid = threadIdx.x, lane = tid & 63, wid = tid >> 6;
    int wr = wid >> 1, wc = wid & 1;
    int n0 = blockIdx.x * 128, i0 = blockIdx.y * 128;

    f32x4 acc[4][4] = {};

    #define STAGEAV(buf, koff)                                                              \
    {                                                                                       \
        _Pragma("unroll")                                                                   \
        for (int r = 0; r < 4; ++r) {                                                       \
            int c = r * 256 + tid; int row = c >> 3, slot = c & 7;                          \
            GLOAD16(attbf + (size_t)(i0 + row) * 256 + (koff) + ((slot ^ (row & 7)) * 8),   \
                    &As[buf][c * 8]);                                                       \
        }                                                                                   \
        _Pragma("unroll")                                                                   \
        for (int r = 0; r < 4; ++r) {                                                       \
            int c = r * 256 + tid; int row = c >> 3, slot = c & 7;                          \
            GLOAD16(vt + (size_t)(n0 + row) * 256 + (koff) + ((slot ^ (row & 7)) * 8),      \
                    &Bs[buf][c * 8]);                                                       \
        }                                                                                   \
    }

    int cur = 0;
    STAGEAV(0, 0);
    for (int s = 0; s < 4; ++s) {
        __syncthreads();
        if (s < 3) STAGEAV(cur ^ 1, (s + 1) * 64);
        #pragma unroll
        for (int kh = 0; kh < 2; ++kh) {
            bf16x8 a[4], b[4];
            #pragma unroll
            for (int mi = 0; mi < 4; ++mi) {
                int row = wr * 64 + mi * 16 + (lane & 15);
                int slot = (kh * 4 + (lane >> 4)) ^ (row & 7);
                a[mi] = *(const bf16x8*)&As[cur][row * 64 + slot * 8];
            }
            #pragma unroll
            for (int ni = 0; ni < 4; ++ni) {
                int row = wc * 64 + ni * 16 + (lane & 15);
                int slot = (kh * 4 + (lane >> 4)) ^ (row & 7);
                b[ni] = *(const bf16x8*)&Bs[cur][row * 64 + slot * 8];
            }
            #pragma unroll
            for (int mi = 0; mi < 4; ++mi)
                #pragma unroll
                for (int ni = 0; ni < 4; ++ni)
                    acc[mi][ni] = __builtin_amdgcn_mfma_f32_16x16x32_bf16(a[mi], b[ni], acc[mi][ni], 0, 0, 0);
        }
        cur ^= 1;
    }
    #undef STAGEAV

    int r4 = (lane >> 4) * 4, cn = lane & 15;
    #pragma unroll
    for (int mi = 0; mi < 4; ++mi)
        #pragma unroll
        for (int ni = 0; ni < 4; ++ni) {
            int c = n0 + wc * 64 + ni * 16 + cn;
            int kk = c / 768, rem = c - kk * 768;
            int t = rem >> 6, d = rem & 63;
            #pragma unroll
            for (int r = 0; r < 4; ++r) {
                int row = i0 + wr * 64 + mi * 16 + r4 + r;
                bmat[((size_t)row * 12 + t) * 512 + kk * 64 + d] = acc[mi][ni][r];
            }
        }
}

// ---------------------------------------------------------------- K6: y = relu(b@w3T+b3)@w4T+b4
__global__ __launch_bounds__(256) void out_kernel(
    const float* __restrict__ bmat, const float* __restrict__ w3t, const float* __restrict__ b3,
    const float* __restrict__ w4t, const float* __restrict__ b4, float* __restrict__ yout)
{
    int rb = blockIdx.x * 16;     // rows (i*12+t)
    int tid = threadIdx.x;
    __shared__ float rows[16 * 512];
    __shared__ float y1s[16 * 64];
    const float4* src = (const float4*)(bmat + (size_t)rb * 512);
    #pragma unroll
    for (int r = 0; r < 8; ++r) ((float4*)rows)[tid + r * 256] = src[tid + r * 256];
    __syncthreads();

    int dout = tid & 63, rg = tid >> 6;
    float acc[4];
    float b3v = b3[dout];
    #pragma unroll
    for (int jj = 0; jj < 4; ++jj) acc[jj] = b3v;
    for (int c4 = 0; c4 < 128; ++c4) {
        float w0 = w3t[(c4 * 4 + 0) * 64 + dout];
        float w1v = w3t[(c4 * 4 + 1) * 64 + dout];
        float w2v = w3t[(c4 * 4 + 2) * 64 + dout];
        float w3v = w3t[(c4 * 4 + 3) * 64 + dout];
        #pragma unroll
        for (int jj = 0; jj < 4; ++jj) {
            float4 rv = *(const float4*)&rows[(rg * 4 + jj) * 512 + c4 * 4];
            acc[jj] += rv.x * w0 + rv.y * w1v + rv.z * w2v + rv.w * w3v;
        }
    }
    #pragma unroll
    for (int jj = 0; jj < 4; ++jj) y1s[(rg * 4 + jj) * 64 + dout] = fmaxf(acc[jj], 0.f);
    __syncthreads();

    int f = tid & 31, rh = tid >> 5;
    #pragma unroll
    for (int rr = 0; rr < 2; ++rr) {
        int r = rh * 2 + rr;
        float a2 = b4[f];
        #pragma unroll
        for (int dd = 0; dd < 64; ++dd) a2 += y1s[r * 64 + dd] * w4t[dd * 32 + f];
        yout[(size_t)(rb + r) * 32 + f] = a2;
    }
}

// ---------------------------------------------------------------- launch
extern "C" void kernel_launch(void* const* d_in, const int* in_sizes, int n_in,
                              void* d_out, int out_size, void* d_ws, size_t ws_size,
                              hipStream_t stream) {
    (void)in_sizes; (void)n_in; (void)out_size; (void)ws_size;
    const float* x  = (const float*)d_in[0];
    const float* Wq = (const float*)d_in[1];
    const float* Wk = (const float*)d_in[2];
    const float* Wv = (const float*)d_in[3];
    const float* bq = (const float*)d_in[4];
    const float* bk = (const float*)d_in[5];
    const float* bv = (const float*)d_in[6];
    const float* w1 = (const float*)d_in[7];
    const float* b1 = (const float*)d_in[8];
    const float* w2 = (const float*)d_in[9];
    const float* b2 = (const float*)d_in[10];
    const float* w3 = (const float*)d_in[11];
    const float* b3 = (const float*)d_in[12];
    const float* w4 = (const float*)d_in[13];
    const float* b4 = (const float*)d_in[14];

    float* ws = (float*)d_ws;
    // layout (float-slot offsets)
    ushort_t* hpart = (ushort_t*)ws;                     // 16z x 524288 ushorts = [0, 4194304)
    size_t    off   = 4194304;
    ushort_t* qhi   = (ushort_t*)(ws + off);             // 1,572,864 ushorts
    ushort_t* ghi   = (ushort_t*)(ws + off + 786432);    // 12,582,912 ushorts
    ushort_t* vbf   = (ushort_t*)(ws + off + 7077888);   // 1,572,864 ushorts
    ushort_t* vt    = (ushort_t*)(ws + off + 7864320);   // 1,572,864 ushorts
    ushort_t* attbf = (ushort_t*)(ws + off + 8650752);   // 65,536 ushorts
    float*    w3t   = ws + off + 8683520;                // 32,768
    float*    w4t   = ws + off + 8716288;                // 2,048
    float*    bmat  = (float*)ghi;                       // reuse (ghi dead after hgemm)

    float* yout = (float*)d_out;              // 98304
    float* att  = (float*)d_out + 98304;      // 65536

    qkvg_kernel<<<2048, 256, 0, stream>>>(x, Wq, Wk, Wv, bq, bk, bv, w1, qhi, vbf, ghi);
    prep_kernel<<<401, 256, 0, stream>>>(vbf, w3, w4, vt, w3t, w4t);
    hgemm_kernel<<<512, 256, 0, stream>>>(qhi, ghi, hpart);
    score_softmax_kernel<<<256, 256, 0, stream>>>(hpart, b1, w2, b2, att, attbf);
    av_kernel<<<dim3(48, 2), 256, 0, stream>>>(attbf, vt, bmat);
    out_kernel<<<192, 256, 0, stream>>>(bmat, w3t, b3, w4t, b4, yout);
}

// Round 7
// 80.755 us; speedup vs baseline: 4.4720x; 1.0295x over previous
//
#include <hip/hip_runtime.h>
#include <hip/hip_bf16.h>

// N=256, T=12, F=32, T_dim=8, D=64;  c-index: c = kk*768 + t*64 + d  (size 6144)
typedef unsigned short ushort_t;
typedef __bf16 bf16x8 __attribute__((ext_vector_type(8)));
typedef float f32x4 __attribute__((ext_vector_type(4)));
typedef ushort_t ushort8 __attribute__((ext_vector_type(8)));

#define GLOAD16(gp, lp) \
    __builtin_amdgcn_global_load_lds((const __attribute__((address_space(1))) void*)(gp), \
                                     (__attribute__((address_space(3))) void*)(lp), 16, 0, 0)

__device__ __forceinline__ ushort_t bf16bits(float x) {
    __hip_bfloat16 h = __float2bfloat16(x);
    return *(ushort_t*)&h;
}
__device__ __forceinline__ float bf2f(ushort_t u) {
    unsigned v = (unsigned)u << 16;
    float f;
    __builtin_memcpy(&f, &v, 4);
    return f;
}

// ---------------------------------------------------------------- K1: fused QKV projection + G build
// block b = j*8+kk; weights staged to LDS via global_load_lds (async DMA, no VGPR round-trip)
__global__ __launch_bounds__(256) void qkvg_kernel(
    const float* __restrict__ x,
    const float* __restrict__ Wq, const float* __restrict__ Wk, const float* __restrict__ Wv,
    const float* __restrict__ bq, const float* __restrict__ bk, const float* __restrict__ bv,
    const float* __restrict__ w1,
    ushort_t* __restrict__ qhi, ushort_t* __restrict__ vbf, ushort_t* __restrict__ ghi)
{
    __shared__ float xs[384];
    __shared__ float wsm[3 * 2048];   // Wq|Wk|Wv slab for this b, row-major [f][d]
    __shared__ float ks[768];         // k[b]: [t][d]
    __shared__ float w1s[1152];       // w1[m][kk*144 + z]
    int b = blockIdx.x;               // 0..2047
    int j = b >> 3, kk = b & 7;
    int tid = threadIdx.x;

    // async-stage three 8KB weight slabs: 6 x (256 lanes x 16B)
    {
        const size_t base = (size_t)b * 2048;
        #pragma unroll
        for (int r = 0; r < 2; ++r) {
            int c = r * 256 + tid;
            GLOAD16(Wq + base + c * 4, &wsm[c * 4]);
            GLOAD16(Wk + base + c * 4, &wsm[2048 + c * 4]);
            GLOAD16(Wv + base + c * 4, &wsm[4096 + c * 4]);
        }
    }
    if (tid < 96) ((float4*)xs)[tid] = ((const float4*)(x + j * 384))[tid];
    for (int e = tid; e < 1152; e += 256)
        w1s[e] = w1[(e / 144) * 1152 + kk * 144 + (e % 144)];
    __syncthreads();   // drains vmcnt (incl. global_load_lds) + lgkm

    int d = tid & 63, tg = tid >> 6;
    float aq[3] = {0.f,0.f,0.f}, ak[3] = {0.f,0.f,0.f}, av[3] = {0.f,0.f,0.f};
    #pragma unroll 8
    for (int f = 0; f < 32; ++f) {
        float wq = wsm[f * 64 + d];            // lanes consecutive -> 2-way alias, free
        float wk = wsm[2048 + f * 64 + d];
        float wv = wsm[4096 + f * 64 + d];
        #pragma unroll
        for (int tt = 0; tt < 3; ++tt) {
            float xv = xs[(tg + tt * 4) * 32 + f];
            aq[tt] += xv * wq; ak[tt] += xv * wk; av[tt] += xv * wv;
        }
    }
    float bqv = bq[b * 64 + d], bkv = bk[b * 64 + d], bvv = bv[b * 64 + d];
    #pragma unroll
    for (int tt = 0; tt < 3; ++tt) {
        int t = tg + tt * 4;
        size_t o = ((size_t)b * 12 + t) * 64 + d;
        qhi[o] = bf16bits(0.125f * (aq[tt] + bqv));
        float kv = ak[tt] + bkv;
        ks[t * 64 + d] = kv;
        vbf[o] = bf16bits(av[tt] + bvv);
    }
    __syncthreads();

    // G-build: 768 ushort8 outputs / 256 threads = 3 each
    #pragma unroll
    for (int r = 0; r < 3; ++r) {
        int e = r * 256 + tid;               // (m, t, d8)
        int m = e / 96, rem = e - m * 96;
        int t = rem >> 3, d8 = rem & 7;
        const float* w1p = w1s + m * 144 + t * 12;
        float acc[8] = {0.f,0.f,0.f,0.f,0.f,0.f,0.f,0.f};
        #pragma unroll
        for (int s = 0; s < 12; ++s) {
            float wv = w1p[s];
            const float4* kp = (const float4*)(ks + s * 64 + d8 * 8);
            float4 k0 = kp[0], k1 = kp[1];
            acc[0] += wv * k0.x; acc[1] += wv * k0.y;
            acc[2] += wv * k0.z; acc[3] += wv * k0.w;
            acc[4] += wv * k1.x; acc[5] += wv * k1.y;
            acc[6] += wv * k1.z; acc[7] += wv * k1.w;
        }
        ushort8 u;
        #pragma unroll
        for (int dd = 0; dd < 8; ++dd) u[dd] = bf16bits(acc[dd]);
        *(ushort8*)(ghi + ((size_t)j * 8 + m) * 6144 + kk * 768 + t * 64 + d8 * 8) = u;
    }
}

// ---------------------------------------------------------------- K2: H GEMM (blocks 0..511) + prep tail (512..912)
// H[i][(j,m)] = Qhi . G ; block 128x128, 4 waves 64x64, BK=32, nz=16 K-split
// XCD-aware z-major mapping; prep blocks: vt transpose (512..895), w3t (896..911), w4t (912)
__global__ __launch_bounds__(256, 2) void hgemm_kernel(
    const ushort_t* __restrict__ qhi, const ushort_t* __restrict__ ghi,
    ushort_t* __restrict__ hpart,
    const ushort_t* __restrict__ vbf, const float* __restrict__ w3, const float* __restrict__ w4,
    ushort_t* __restrict__ vt, float* __restrict__ w3t, float* __restrict__ w4t)
{
    __shared__ ushort_t As[2][128 * 32];
    __shared__ ushort_t Bs[2][128 * 32];

    int tid = threadIdx.x;
    int bid = blockIdx.x;                 // 0..912

    if (bid >= 512) {
        if (bid < 896) {
            // vbf [j][6144] -> vt[c][j]; 16 c-cols x 256 j per block
            ushort_t (*ts)[264] = (ushort_t(*)[264])As;
            int c0 = (bid - 512) * 16;
            int cc = tid & 15, jg = tid >> 4;
            #pragma unroll 4
            for (int jj = 0; jj < 16; ++jj) {
                int jx = jg * 16 + jj;
                ts[cc][jx] = vbf[(size_t)jx * 6144 + c0 + cc];
            }
            __syncthreads();
            #pragma unroll
            for (int c = 0; c < 16; ++c)
                vt[(size_t)(c0 + c) * 256 + tid] = ts[c][tid];
            return;
        }
        if (bid < 912) {
            // w3 (64 dout x 512 c3, c3=d*8+kk) -> w3t[cb*64+dout], cb = kk*64+d
            int wb = bid - 896;
            #pragma unroll
            for (int r = 0; r < 8; ++r) {
                int e = wb * 2048 + r * 256 + tid;
                int dout = e >> 9, c3 = e & 511;
                int cb = ((c3 & 7) << 6) | (c3 >> 3);
                w3t[cb * 64 + dout] = w3[e];
            }
            return;
        }
        #pragma unroll
        for (int r = 0; r < 8; ++r) {
            int e = r * 256 + tid; int f = e >> 6, dd = e & 63;
            w4t[dd * 32 + f] = w4[e];
        }
        return;
    }

    int lane = tid & 63, wid = tid >> 6;
    int wr = wid >> 1, wc = wid & 1;
    int xcd = bid & 7, kq = bid >> 3;     // kq 0..63
    int z = xcd + 8 * (kq >> 5);
    int rem = kq & 31;
    int n0 = (rem & 15) * 128, i0 = (rem >> 4) * 128;
    int kbase = z * 384;
    ushort_t* Hout = hpart + (size_t)z * 524288;

    f32x4 acc[4][4] = {};

    #define STAGE(buf, koff)                                                                 \
    {                                                                                        \
        _Pragma("unroll")                                                                    \
        for (int r = 0; r < 2; ++r) {                                                        \
            int c = r * 256 + tid; int row = c >> 2, slot = c & 3;                           \
            int so = (koff) + ((slot ^ ((row >> 1) & 3)) * 8);                               \
            GLOAD16(qhi + (size_t)(i0 + row) * 6144 + so, &As[buf][c * 8]);                  \
            GLOAD16(ghi + (size_t)(n0 + row) * 6144 + so, &Bs[buf][c * 8]);                  \
        }                                                                                    \
    }

    STAGE(0, kbase);
    int cur = 0;
    for (int s = 0; s < 12; ++s) {
        __syncthreads();
        if (s + 1 < 12) STAGE(cur ^ 1, kbase + (s + 1) * 32);
        bf16x8 a[4], b[4];
        #pragma unroll
        for (int ni = 0; ni < 4; ++ni) {
            int row = wc * 64 + ni * 16 + (lane & 15);
            int slot = (lane >> 4) ^ ((row >> 1) & 3);
            b[ni] = *(const bf16x8*)&Bs[cur][row * 32 + slot * 8];
        }
        #pragma unroll
        for (int mi = 0; mi < 4; ++mi) {
            int row = wr * 64 + mi * 16 + (lane & 15);
            int slot = (lane >> 4) ^ ((row >> 1) & 3);
            a[mi] = *(const bf16x8*)&As[cur][row * 32 + slot * 8];
        }
        #pragma unroll
        for (int mi = 0; mi < 4; ++mi)
            #pragma unroll
            for (int ni = 0; ni < 4; ++ni)
                acc[mi][ni] = __builtin_amdgcn_mfma_f32_16x16x32_bf16(a[mi], b[ni], acc[mi][ni], 0, 0, 0);
        cur ^= 1;
    }
    #undef STAGE

    int r4 = (lane >> 4) * 4, cn = lane & 15;
    #pragma unroll
    for (int mi = 0; mi < 4; ++mi)
        #pragma unroll
        for (int ni = 0; ni < 4; ++ni)
            #pragma unroll
            for (int r = 0; r < 4; ++r) {
                int row = i0 + wr * 64 + mi * 16 + r4 + r;
                int col = n0 + wc * 64 + ni * 16 + cn;
                Hout[(size_t)row * 2048 + col] = bf16bits(acc[mi][ni][r]);
            }
}

// ---------------------------------------------------------------- K3: z-reduce + score + softmax (+ bf16 att)
__global__ __launch_bounds__(256) void score_softmax_kernel(
    const ushort_t* __restrict__ hpart, const float* __restrict__ b1g,
    const float* __restrict__ w2g, const float* __restrict__ b2g,
    float* __restrict__ att, ushort_t* __restrict__ attbf)
{
    int i = blockIdx.x, j = threadIdx.x;
    float hm[8];
    #pragma unroll
    for (int m = 0; m < 8; ++m) hm[m] = b1g[m];
    #pragma unroll 4
    for (int z = 0; z < 16; ++z) {
        ushort8 u = *(const ushort8*)(hpart + (size_t)z * 524288 + (size_t)i * 2048 + j * 8);
        #pragma unroll
        for (int m = 0; m < 8; ++m) hm[m] += bf2f(u[m]);
    }
    float sv = b2g[0];
    #pragma unroll
    for (int m = 0; m < 8; ++m) sv += fmaxf(hm[m], 0.f) * w2g[m];

    __shared__ float wred[4], wred2[4];
    float mx = sv;
    #pragma unroll
    for (int off = 32; off > 0; off >>= 1) mx = fmaxf(mx, __shfl_down(mx, off, 64));
    if ((j & 63) == 0) wred[j >> 6] = mx;
    __syncthreads();
    mx = fmaxf(fmaxf(wred[0], wred[1]), fmaxf(wred[2], wred[3]));

    float e = expf(sv - mx);
    float sum = e;
    #pragma unroll
    for (int off = 32; off > 0; off >>= 1) sum += __shfl_down(sum, off, 64);
    if ((j & 63) == 0) wred2[j >> 6] = sum;
    __syncthreads();
    sum = wred2[0] + wred2[1] + wred2[2] + wred2[3];

    float pv = e / sum;
    att[(size_t)i * 256 + j] = pv;
    attbf[(size_t)i * 256 + j] = bf16bits(pv);
}

// ---------------------------------------------------------------- K4: b = att @ v via MFMA
__global__ __launch_bounds__(256) void av_kernel(
    const ushort_t* __restrict__ attbf, const ushort_t* __restrict__ vt,
    float* __restrict__ bmat)
{
    __shared__ ushort_t As[2][128 * 64];
    __shared__ ushort_t Bs[2][128 * 64];

    int tid = threadIdx.x, lane = tid & 63, wid = tid >> 6;
    int wr = wid >> 1, wc = wid & 1;
    int n0 = blockIdx.x * 128, i0 = blockIdx.y * 128;

    f32x4 acc[4][4] = {};

    #define STAGEAV(buf, koff)                                                              \
    {                                                                                       \
        _Pragma("unroll")                                                                   \
        for (int r = 0; r < 4; ++r) {                                                       \
            int c = r * 256 + tid; int row = c >> 3, slot = c & 7;                          \
            GLOAD16(attbf + (size_t)(i0 + row) * 256 + (koff) + ((slot ^ (row & 7)) * 8),   \
                    &As[buf][c * 8]);                                                       \
        }                                                                                   \
        _Pragma("unroll")                                                                   \
        for (int r = 0; r < 4; ++r) {                                                       \
            int c = r * 256 + tid; int row = c >> 3, slot = c & 7;                          \
            GLOAD16(vt + (size_t)(n0 + row) * 256 + (koff) + ((slot ^ (row & 7)) * 8),      \
                    &Bs[buf][c * 8]);                                                       \
        }                                                                                   \
    }

    int cur = 0;
    STAGEAV(0, 0);
    for (int s = 0; s < 4; ++s) {
        __syncthreads();
        if (s < 3) STAGEAV(cur ^ 1, (s + 1) * 64);
        #pragma unroll
        for (int kh = 0; kh < 2; ++kh) {
            bf16x8 a[4], b[4];
            #pragma unroll
            for (int mi = 0; mi < 4; ++mi) {
                int row = wr * 64 + mi * 16 + (lane & 15);
                int slot = (kh * 4 + (lane >> 4)) ^ (row & 7);
                a[mi] = *(const bf16x8*)&As[cur][row * 64 + slot * 8];
            }
            #pragma unroll
            for (int ni = 0; ni < 4; ++ni) {
                int row = wc * 64 + ni * 16 + (lane & 15);
                int slot = (kh * 4 + (lane >> 4)) ^ (row & 7);
                b[ni] = *(const bf16x8*)&Bs[cur][row * 64 + slot * 8];
            }
            #pragma unroll
            for (int mi = 0; mi < 4; ++mi)
                #pragma unroll
                for (int ni = 0; ni < 4; ++ni)
                    acc[mi][ni] = __builtin_amdgcn_mfma_f32_16x16x32_bf16(a[mi], b[ni], acc[mi][ni], 0, 0, 0);
        }
        cur ^= 1;
    }
    #undef STAGEAV

    int r4 = (lane >> 4) * 4, cn = lane & 15;
    #pragma unroll
    for (int mi = 0; mi < 4; ++mi)
        #pragma unroll
        for (int ni = 0; ni < 4; ++ni) {
            int c = n0 + wc * 64 + ni * 16 + cn;
            int kk = c / 768, rem = c - kk * 768;
            int t = rem >> 6, d = rem & 63;
            #pragma unroll
            for (int r = 0; r < 4; ++r) {
                int row = i0 + wr * 64 + mi * 16 + r4 + r;
                bmat[((size_t)row * 12 + t) * 512 + kk * 64 + d] = acc[mi][ni][r];
            }
        }
}

// ---------------------------------------------------------------- K5: y = relu(b@w3T+b3)@w4T+b4
__global__ __launch_bounds__(256) void out_kernel(
    const float* __restrict__ bmat, const float* __restrict__ w3t, const float* __restrict__ b3,
    const float* __restrict__ w4t, const float* __restrict__ b4, float* __restrict__ yout)
{
    int rb = blockIdx.x * 16;     // rows (i*12+t)
    int tid = threadIdx.x;
    __shared__ float rows[16 * 512];
    __shared__ float y1s[16 * 64];
    const float4* src = (const float4*)(bmat + (size_t)rb * 512);
    #pragma unroll
    for (int r = 0; r < 8; ++r) ((float4*)rows)[tid + r * 256] = src[tid + r * 256];
    __syncthreads();

    int dout = tid & 63, rg = tid >> 6;
    float acc[4];
    float b3v = b3[dout];
    #pragma unroll
    for (int jj = 0; jj < 4; ++jj) acc[jj] = b3v;
    for (int c4 = 0; c4 < 128; ++c4) {
        float w0 = w3t[(c4 * 4 + 0) * 64 + dout];
        float w1v = w3t[(c4 * 4 + 1) * 64 + dout];
        float w2v = w3t[(c4 * 4 + 2) * 64 + dout];
        float w3v = w3t[(c4 * 4 + 3) * 64 + dout];
        #pragma unroll
        for (int jj = 0; jj < 4; ++jj) {
            float4 rv = *(const float4*)&rows[(rg * 4 + jj) * 512 + c4 * 4];
            acc[jj] += rv.x * w0 + rv.y * w1v + rv.z * w2v + rv.w * w3v;
        }
    }
    #pragma unroll
    for (int jj = 0; jj < 4; ++jj) y1s[(rg * 4 + jj) * 64 + dout] = fmaxf(acc[jj], 0.f);
    __syncthreads();

    int f = tid & 31, rh = tid >> 5;
    #pragma unroll
    for (int rr = 0; rr < 2; ++rr) {
        int r = rh * 2 + rr;
        float a2 = b4[f];
        #pragma unroll
        for (int dd = 0; dd < 64; ++dd) a2 += y1s[r * 64 + dd] * w4t[dd * 32 + f];
        yout[(size_t)(rb + r) * 32 + f] = a2;
    }
}

// ---------------------------------------------------------------- launch
extern "C" void kernel_launch(void* const* d_in, const int* in_sizes, int n_in,
                              void* d_out, int out_size, void* d_ws, size_t ws_size,
                              hipStream_t stream) {
    (void)in_sizes; (void)n_in; (void)out_size; (void)ws_size;
    const float* x  = (const float*)d_in[0];
    const float* Wq = (const float*)d_in[1];
    const float* Wk = (const float*)d_in[2];
    const float* Wv = (const float*)d_in[3];
    const float* bq = (const float*)d_in[4];
    const float* bk = (const float*)d_in[5];
    const float* bv = (const float*)d_in[6];
    const float* w1 = (const float*)d_in[7];
    const float* b1 = (const float*)d_in[8];
    const float* w2 = (const float*)d_in[9];
    const float* b2 = (const float*)d_in[10];
    const float* w3 = (const float*)d_in[11];
    const float* b3 = (const float*)d_in[12];
    const float* w4 = (const float*)d_in[13];
    const float* b4 = (const float*)d_in[14];

    float* ws = (float*)d_ws;
    // layout (float-slot offsets)
    ushort_t* hpart = (ushort_t*)ws;                     // 16z x 524288 ushorts = [0, 4194304)
    size_t    off   = 4194304;
    ushort_t* qhi   = (ushort_t*)(ws + off);             // 1,572,864 ushorts
    ushort_t* ghi   = (ushort_t*)(ws + off + 786432);    // 12,582,912 ushorts
    ushort_t* vbf   = (ushort_t*)(ws + off + 7077888);   // 1,572,864 ushorts
    ushort_t* vt    = (ushort_t*)(ws + off + 7864320);   // 1,572,864 ushorts
    ushort_t* attbf = (ushort_t*)(ws + off + 8650752);   // 65,536 ushorts
    float*    w3t   = ws + off + 8683520;                // 32,768
    float*    w4t   = ws + off + 8716288;                // 2,048
    float*    bmat  = (float*)ghi;                       // reuse (ghi dead after hgemm)

    float* yout = (float*)d_out;              // 98304
    float* att  = (float*)d_out + 98304;      // 65536

    qkvg_kernel<<<2048, 256, 0, stream>>>(x, Wq, Wk, Wv, bq, bk, bv, w1, qhi, vbf, ghi);
    hgemm_kernel<<<913, 256, 0, stream>>>(qhi, ghi, hpart, vbf, w3, w4, vt, w3t, w4t);
    score_softmax_kernel<<<256, 256, 0, stream>>>(hpart, b1, w2, b2, att, attbf);
    av_kernel<<<dim3(48, 2), 256, 0, stream>>>(attbf, vt, bmat);
    out_kernel<<<192, 256, 0, stream>>>(bmat, w3t, b3, w4t, b4, yout);
}

// Round 8
// 79.028 us; speedup vs baseline: 4.5697x; 1.0219x over previous
//
#include <hip/hip_runtime.h>
#include <hip/hip_bf16.h>

// N=256, T=12, F=32, T_dim=8, D=64;  c-index: c = kk*768 + t*64 + d  (size 6144)
typedef unsigned short ushort_t;
typedef __bf16 bf16x8 __attribute__((ext_vector_type(8)));
typedef float f32x4 __attribute__((ext_vector_type(4)));
typedef ushort_t ushort8 __attribute__((ext_vector_type(8)));

#define GLOAD16(gp, lp) \
    __builtin_amdgcn_global_load_lds((const __attribute__((address_space(1))) void*)(gp), \
                                     (__attribute__((address_space(3))) void*)(lp), 16, 0, 0)

__device__ __forceinline__ ushort_t bf16bits(float x) {
    __hip_bfloat16 h = __float2bfloat16(x);
    return *(ushort_t*)&h;
}
__device__ __forceinline__ float bf2f(ushort_t u) {
    unsigned v = (unsigned)u << 16;
    float f;
    __builtin_memcpy(&f, &v, 4);
    return f;
}

// ---------------------------------------------------------------- K1: QKV projection, one block per (b, matrix)
// grid 6144; all outputs bf16 (q scaled by 0.125)
__global__ __launch_bounds__(256) void qkv_kernel(
    const float* __restrict__ x,
    const float* __restrict__ Wq, const float* __restrict__ Wk, const float* __restrict__ Wv,
    const float* __restrict__ bq, const float* __restrict__ bk, const float* __restrict__ bv,
    ushort_t* __restrict__ qhi, ushort_t* __restrict__ kbf, ushort_t* __restrict__ vbf)
{
    int bx = blockIdx.x;               // 0..6143
    int b = bx / 3, mat = bx - b * 3;  // b 0..2047
    int j = b >> 3;
    __shared__ float xs[384];
    int tid = threadIdx.x;
    if (tid < 96) ((float4*)xs)[tid] = ((const float4*)(x + j * 384))[tid];
    __syncthreads();

    const float* W    = (mat == 0) ? Wq : (mat == 1) ? Wk : Wv;
    const float* bias = (mat == 0) ? bq : (mat == 1) ? bk : bv;
    ushort_t*    out  = (mat == 0) ? qhi : (mat == 1) ? kbf : vbf;
    float scale = (mat == 0) ? 0.125f : 1.0f;

    int d = tid & 63, tg = tid >> 6;   // t = tg, tg+4, tg+8
    const float* wb = W + (size_t)b * 2048 + d;
    const float4* xs4 = (const float4*)xs;
    float a0 = 0.f, a1 = 0.f, a2 = 0.f;
    #pragma unroll
    for (int f4 = 0; f4 < 8; ++f4) {
        float w0 = wb[(f4 * 4 + 0) * 64];
        float w1v = wb[(f4 * 4 + 1) * 64];
        float w2v = wb[(f4 * 4 + 2) * 64];
        float w3v = wb[(f4 * 4 + 3) * 64];
        float4 x0 = xs4[tg * 8 + f4];
        float4 x1 = xs4[(tg + 4) * 8 + f4];
        float4 x2 = xs4[(tg + 8) * 8 + f4];
        a0 += x0.x * w0 + x0.y * w1v + x0.z * w2v + x0.w * w3v;
        a1 += x1.x * w0 + x1.y * w1v + x1.z * w2v + x1.w * w3v;
        a2 += x2.x * w0 + x2.y * w1v + x2.z * w2v + x2.w * w3v;
    }
    float bv_ = bias[b * 64 + d];
    size_t o = (size_t)b * 768 + d;
    out[o + (size_t)tg * 64]       = bf16bits((a0 + bv_) * scale);
    out[o + (size_t)(tg + 4) * 64] = bf16bits((a1 + bv_) * scale);
    out[o + (size_t)(tg + 8) * 64] = bf16bits((a2 + bv_) * scale);
}

// ---------------------------------------------------------------- K2: G build, one block per b=(j,kk)
// G[(j*8+m)][kk*768+t*64+d] = sum_s w1[m][kk*144+t*12+s] * k[j*8+kk][s][d]
__global__ __launch_bounds__(256) void gbuild_kernel(
    const ushort_t* __restrict__ kbf, const float* __restrict__ w1,
    ushort_t* __restrict__ ghi)
{
    __shared__ float w1s[1152];   // [m][144] slab for this kk
    __shared__ float ks[768];     // k row fp32
    int b = blockIdx.x, j = b >> 3, kk = b & 7;
    int tid = threadIdx.x;

    // stage w1 slab via async DMA: 288 x 16B chunks (lane-contiguous dest)
    #pragma unroll
    for (int r = 0; r < 2; ++r) {
        int c = r * 256 + tid;
        if (c < 288)
            GLOAD16(w1 + (c / 36) * 1152 + kk * 144 + (c % 36) * 4, &w1s[c * 4]);
    }
    // stage k row: bf16 -> fp32
    if (tid < 96) {
        ushort8 u = *(const ushort8*)(kbf + (size_t)b * 768 + tid * 8);
        float4 f0, f1;
        f0.x = bf2f(u[0]); f0.y = bf2f(u[1]); f0.z = bf2f(u[2]); f0.w = bf2f(u[3]);
        f1.x = bf2f(u[4]); f1.y = bf2f(u[5]); f1.z = bf2f(u[6]); f1.w = bf2f(u[7]);
        ((float4*)ks)[tid * 2]     = f0;
        ((float4*)ks)[tid * 2 + 1] = f1;
    }
    __syncthreads();

    // 768 ushort8 outputs / 256 threads = 3 each
    #pragma unroll
    for (int r = 0; r < 3; ++r) {
        int e = r * 256 + tid;               // (m, t, d8)
        int m = e / 96, rem = e - m * 96;
        int t = rem >> 3, d8 = rem & 7;
        const float* w1p = w1s + m * 144 + t * 12;
        float acc[8] = {0.f,0.f,0.f,0.f,0.f,0.f,0.f,0.f};
        #pragma unroll
        for (int s = 0; s < 12; ++s) {
            float wv = w1p[s];
            const float4* kp = (const float4*)(ks + s * 64 + d8 * 8);
            float4 k0 = kp[0], k1 = kp[1];
            acc[0] += wv * k0.x; acc[1] += wv * k0.y;
            acc[2] += wv * k0.z; acc[3] += wv * k0.w;
            acc[4] += wv * k1.x; acc[5] += wv * k1.y;
            acc[6] += wv * k1.z; acc[7] += wv * k1.w;
        }
        ushort8 u;
        #pragma unroll
        for (int dd = 0; dd < 8; ++dd) u[dd] = bf16bits(acc[dd]);
        *(ushort8*)(ghi + ((size_t)j * 8 + m) * 6144 + kk * 768 + t * 64 + d8 * 8) = u;
    }
}

// ---------------------------------------------------------------- K3: H GEMM (blocks 0..511) + prep tail (512..912)
// H[i][(j,m)] = Qhi . G ; block 128x128, 4 waves 64x64, BK=32, nz=16 K-split
// XCD-aware z-major mapping; prep blocks: vt transpose (512..895), w3t (896..911), w4t (912)
__global__ __launch_bounds__(256, 2) void hgemm_kernel(
    const ushort_t* __restrict__ qhi, const ushort_t* __restrict__ ghi,
    ushort_t* __restrict__ hpart,
    const ushort_t* __restrict__ vbf, const float* __restrict__ w3, const float* __restrict__ w4,
    ushort_t* __restrict__ vt, float* __restrict__ w3t, float* __restrict__ w4t)
{
    __shared__ ushort_t As[2][128 * 32];
    __shared__ ushort_t Bs[2][128 * 32];

    int tid = threadIdx.x;
    int bid = blockIdx.x;                 // 0..912

    if (bid >= 512) {
        if (bid < 896) {
            // vbf [j][6144] -> vt[c][j]; 16 c-cols x 256 j per block
            ushort_t (*ts)[264] = (ushort_t(*)[264])As;
            int c0 = (bid - 512) * 16;
            int cc = tid & 15, jg = tid >> 4;
            #pragma unroll 4
            for (int jj = 0; jj < 16; ++jj) {
                int jx = jg * 16 + jj;
                ts[cc][jx] = vbf[(size_t)jx * 6144 + c0 + cc];
            }
            __syncthreads();
            #pragma unroll
            for (int c = 0; c < 16; ++c)
                vt[(size_t)(c0 + c) * 256 + tid] = ts[c][tid];
            return;
        }
        if (bid < 912) {
            // w3 (64 dout x 512 c3, c3=d*8+kk) -> w3t[cb*64+dout], cb = kk*64+d
            int wb = bid - 896;
            #pragma unroll
            for (int r = 0; r < 8; ++r) {
                int e = wb * 2048 + r * 256 + tid;
                int dout = e >> 9, c3 = e & 511;
                int cb = ((c3 & 7) << 6) | (c3 >> 3);
                w3t[cb * 64 + dout] = w3[e];
            }
            return;
        }
        #pragma unroll
        for (int r = 0; r < 8; ++r) {
            int e = r * 256 + tid; int f = e >> 6, dd = e & 63;
            w4t[dd * 32 + f] = w4[e];
        }
        return;
    }

    int lane = tid & 63, wid = tid >> 6;
    int wr = wid >> 1, wc = wid & 1;
    int xcd = bid & 7, kq = bid >> 3;     // kq 0..63
    int z = xcd + 8 * (kq >> 5);
    int rem = kq & 31;
    int n0 = (rem & 15) * 128, i0 = (rem >> 4) * 128;
    int kbase = z * 384;
    ushort_t* Hout = hpart + (size_t)z * 524288;

    f32x4 acc[4][4] = {};

    #define STAGE(buf, koff)                                                                 \
    {                                                                                        \
        _Pragma("unroll")                                                                    \
        for (int r = 0; r < 2; ++r) {                                                        \
            int c = r * 256 + tid; int row = c >> 2, slot = c & 3;                           \
            int so = (koff) + ((slot ^ ((row >> 1) & 3)) * 8);                               \
            GLOAD16(qhi + (size_t)(i0 + row) * 6144 + so, &As[buf][c * 8]);                  \
            GLOAD16(ghi + (size_t)(n0 + row) * 6144 + so, &Bs[buf][c * 8]);                  \
        }                                                                                    \
    }

    STAGE(0, kbase);
    int cur = 0;
    for (int s = 0; s < 12; ++s) {
        __syncthreads();
        if (s + 1 < 12) STAGE(cur ^ 1, kbase + (s + 1) * 32);
        bf16x8 a[4], b[4];
        #pragma unroll
        for (int ni = 0; ni < 4; ++ni) {
            int row = wc * 64 + ni * 16 + (lane & 15);
            int slot = (lane >> 4) ^ ((row >> 1) & 3);
            b[ni] = *(const bf16x8*)&Bs[cur][row * 32 + slot * 8];
        }
        #pragma unroll
        for (int mi = 0; mi < 4; ++mi) {
            int row = wr * 64 + mi * 16 + (lane & 15);
            int slot = (lane >> 4) ^ ((row >> 1) & 3);
            a[mi] = *(const bf16x8*)&As[cur][row * 32 + slot * 8];
        }
        #pragma unroll
        for (int mi = 0; mi < 4; ++mi)
            #pragma unroll
            for (int ni = 0; ni < 4; ++ni)
                acc[mi][ni] = __builtin_amdgcn_mfma_f32_16x16x32_bf16(a[mi], b[ni], acc[mi][ni], 0, 0, 0);
        cur ^= 1;
    }
    #undef STAGE

    int r4 = (lane >> 4) * 4, cn = lane & 15;
    #pragma unroll
    for (int mi = 0; mi < 4; ++mi)
        #pragma unroll
        for (int ni = 0; ni < 4; ++ni)
            #pragma unroll
            for (int r = 0; r < 4; ++r) {
                int row = i0 + wr * 64 + mi * 16 + r4 + r;
                int col = n0 + wc * 64 + ni * 16 + cn;
                Hout[(size_t)row * 2048 + col] = bf16bits(acc[mi][ni][r]);
            }
}

// ---------------------------------------------------------------- K4: z-reduce + score + softmax (+ bf16 att)
__global__ __launch_bounds__(256) void score_softmax_kernel(
    const ushort_t* __restrict__ hpart, const float* __restrict__ b1g,
    const float* __restrict__ w2g, const float* __restrict__ b2g,
    float* __restrict__ att, ushort_t* __restrict__ attbf)
{
    int i = blockIdx.x, j = threadIdx.x;
    float hm[8];
    #pragma unroll
    for (int m = 0; m < 8; ++m) hm[m] = b1g[m];
    #pragma unroll 4
    for (int z = 0; z < 16; ++z) {
        ushort8 u = *(const ushort8*)(hpart + (size_t)z * 524288 + (size_t)i * 2048 + j * 8);
        #pragma unroll
        for (int m = 0; m < 8; ++m) hm[m] += bf2f(u[m]);
    }
    float sv = b2g[0];
    #pragma unroll
    for (int m = 0; m < 8; ++m) sv += fmaxf(hm[m], 0.f) * w2g[m];

    __shared__ float wred[4], wred2[4];
    float mx = sv;
    #pragma unroll
    for (int off = 32; off > 0; off >>= 1) mx = fmaxf(mx, __shfl_down(mx, off, 64));
    if ((j & 63) == 0) wred[j >> 6] = mx;
    __syncthreads();
    mx = fmaxf(fmaxf(wred[0], wred[1]), fmaxf(wred[2], wred[3]));

    float e = expf(sv - mx);
    float sum = e;
    #pragma unroll
    for (int off = 32; off > 0; off >>= 1) sum += __shfl_down(sum, off, 64);
    if ((j & 63) == 0) wred2[j >> 6] = sum;
    __syncthreads();
    sum = wred2[0] + wred2[1] + wred2[2] + wred2[3];

    float pv = e / sum;
    att[(size_t)i * 256 + j] = pv;
    attbf[(size_t)i * 256 + j] = bf16bits(pv);
}

// ---------------------------------------------------------------- K5: b = att @ v via MFMA
__global__ __launch_bounds__(256) void av_kernel(
    const ushort_t* __restrict__ attbf, const ushort_t* __restrict__ vt,
    float* __restrict__ bmat)
{
    __shared__ ushort_t As[2][128 * 64];
    __shared__ ushort_t Bs[2][128 * 64];

    int tid = threadIdx.x, lane = tid & 63, wid = tid >> 6;
    int wr = wid >> 1, wc = wid & 1;
    int n0 = blockIdx.x * 128, i0 = blockIdx.y * 128;

    f32x4 acc[4][4] = {};

    #define STAGEAV(buf, koff)                                                              \
    {                                                                                       \
        _Pragma("unroll")                                                                   \
        for (int r = 0; r < 4; ++r) {                                                       \
            int c = r * 256 + tid; int row = c >> 3, slot = c & 7;                          \
            GLOAD16(attbf + (size_t)(i0 + row) * 256 + (koff) + ((slot ^ (row & 7)) * 8),   \
                    &As[buf][c * 8]);                                                       \
        }                                                                                   \
        _Pragma("unroll")                                                                   \
        for (int r = 0; r < 4; ++r) {                                                       \
            int c = r * 256 + tid; int row = c >> 3, slot = c & 7;                          \
            GLOAD16(vt + (size_t)(n0 + row) * 256 + (koff) + ((slot ^ (row & 7)) * 8),      \
                    &Bs[buf][c * 8]);                                                       \
        }                                                                                   \
    }

    int cur = 0;
    STAGEAV(0, 0);
    for (int s = 0; s < 4; ++s) {
        __syncthreads();
        if (s < 3) STAGEAV(cur ^ 1, (s + 1) * 64);
        #pragma unroll
        for (int kh = 0; kh < 2; ++kh) {
            bf16x8 a[4], b[4];
            #pragma unroll
            for (int mi = 0; mi < 4; ++mi) {
                int row = wr * 64 + mi * 16 + (lane & 15);
                int slot = (kh * 4 + (lane >> 4)) ^ (row & 7);
                a[mi] = *(const bf16x8*)&As[cur][row * 64 + slot * 8];
            }
            #pragma unroll
            for (int ni = 0; ni < 4; ++ni) {
                int row = wc * 64 + ni * 16 + (lane & 15);
                int slot = (kh * 4 + (lane >> 4)) ^ (row & 7);
                b[ni] = *(const bf16x8*)&Bs[cur][row * 64 + slot * 8];
            }
            #pragma unroll
            for (int mi = 0; mi < 4; ++mi)
                #pragma unroll
                for (int ni = 0; ni < 4; ++ni)
                    acc[mi][ni] = __builtin_amdgcn_mfma_f32_16x16x32_bf16(a[mi], b[ni], acc[mi][ni], 0, 0, 0);
        }
        cur ^= 1;
    }
    #undef STAGEAV

    int r4 = (lane >> 4) * 4, cn = lane & 15;
    #pragma unroll
    for (int mi = 0; mi < 4; ++mi)
        #pragma unroll
        for (int ni = 0; ni < 4; ++ni) {
            int c = n0 + wc * 64 + ni * 16 + cn;
            int kk = c / 768, rem = c - kk * 768;
            int t = rem >> 6, d = rem & 63;
            #pragma unroll
            for (int r = 0; r < 4; ++r) {
                int row = i0 + wr * 64 + mi * 16 + r4 + r;
                bmat[((size_t)row * 12 + t) * 512 + kk * 64 + d] = acc[mi][ni][r];
            }
        }
}

// ---------------------------------------------------------------- K6: y = relu(b@w3T+b3)@w4T+b4
__global__ __launch_bounds__(256) void out_kernel(
    const float* __restrict__ bmat, const float* __restrict__ w3t, const float* __restrict__ b3,
    const float* __restrict__ w4t, const float* __restrict__ b4, float* __restrict__ yout)
{
    int rb = blockIdx.x * 16;     // rows (i*12+t)
    int tid = threadIdx.x;
    __shared__ float rows[16 * 512];
    __shared__ float y1s[16 * 64];
    const float4* src = (const float4*)(bmat + (size_t)rb * 512);
    #pragma unroll
    for (int r = 0; r < 8; ++r) ((float4*)rows)[tid + r * 256] = src[tid + r * 256];
    __syncthreads();

    int dout = tid & 63, rg = tid >> 6;
    float acc[4];
    float b3v = b3[dout];
    #pragma unroll
    for (int jj = 0; jj < 4; ++jj) acc[jj] = b3v;
    for (int c4 = 0; c4 < 128; ++c4) {
        float w0 = w3t[(c4 * 4 + 0) * 64 + dout];
        float w1v = w3t[(c4 * 4 + 1) * 64 + dout];
        float w2v = w3t[(c4 * 4 + 2) * 64 + dout];
        float w3v = w3t[(c4 * 4 + 3) * 64 + dout];
        #pragma unroll
        for (int jj = 0; jj < 4; ++jj) {
            float4 rv = *(const float4*)&rows[(rg * 4 + jj) * 512 + c4 * 4];
            acc[jj] += rv.x * w0 + rv.y * w1v + rv.z * w2v + rv.w * w3v;
        }
    }
    #pragma unroll
    for (int jj = 0; jj < 4; ++jj) y1s[(rg * 4 + jj) * 64 + dout] = fmaxf(acc[jj], 0.f);
    __syncthreads();

    int f = tid & 31, rh = tid >> 5;
    #pragma unroll
    for (int rr = 0; rr < 2; ++rr) {
        int r = rh * 2 + rr;
        float a2 = b4[f];
        #pragma unroll
        for (int dd = 0; dd < 64; ++dd) a2 += y1s[r * 64 + dd] * w4t[dd * 32 + f];
        yout[(size_t)(rb + r) * 32 + f] = a2;
    }
}

// ---------------------------------------------------------------- launch
extern "C" void kernel_launch(void* const* d_in, const int* in_sizes, int n_in,
                              void* d_out, int out_size, void* d_ws, size_t ws_size,
                              hipStream_t stream) {
    (void)in_sizes; (void)n_in; (void)out_size; (void)ws_size;
    const float* x  = (const float*)d_in[0];
    const float* Wq = (const float*)d_in[1];
    const float* Wk = (const float*)d_in[2];
    const float* Wv = (const float*)d_in[3];
    const float* bq = (const float*)d_in[4];
    const float* bk = (const float*)d_in[5];
    const float* bv = (const float*)d_in[6];
    const float* w1 = (const float*)d_in[7];
    const float* b1 = (const float*)d_in[8];
    const float* w2 = (const float*)d_in[9];
    const float* b2 = (const float*)d_in[10];
    const float* w3 = (const float*)d_in[11];
    const float* b3 = (const float*)d_in[12];
    const float* w4 = (const float*)d_in[13];
    const float* b4 = (const float*)d_in[14];

    float* ws = (float*)d_ws;
    // layout (float-slot offsets)
    ushort_t* hpart = (ushort_t*)ws;                     // 16z x 524288 ushorts = [0, 4194304)
    size_t    off   = 4194304;
    ushort_t* qhi   = (ushort_t*)(ws + off);             // 1,572,864 ushorts
    ushort_t* ghi   = (ushort_t*)(ws + off + 786432);    // 12,582,912 ushorts
    ushort_t* vbf   = (ushort_t*)(ws + off + 7077888);   // 1,572,864 ushorts
    ushort_t* vt    = (ushort_t*)(ws + off + 7864320);   // 1,572,864 ushorts
    ushort_t* attbf = (ushort_t*)(ws + off + 8650752);   // 65,536 ushorts
    float*    w3t   = ws + off + 8683520;                // 32,768
    float*    w4t   = ws + off + 8716288;                // 2,048
    ushort_t* kbf   = (ushort_t*)(ws + off + 8718336);   // 1,572,864 ushorts
    float*    bmat  = (float*)ghi;                       // reuse (ghi dead after hgemm)

    float* yout = (float*)d_out;              // 98304
    float* att  = (float*)d_out + 98304;      // 65536

    qkv_kernel<<<6144, 256, 0, stream>>>(x, Wq, Wk, Wv, bq, bk, bv, qhi, kbf, vbf);
    gbuild_kernel<<<2048, 256, 0, stream>>>(kbf, w1, ghi);
    hgemm_kernel<<<913, 256, 0, stream>>>(qhi, ghi, hpart, vbf, w3, w4, vt, w3t, w4t);
    score_softmax_kernel<<<256, 256, 0, stream>>>(hpart, b1, w2, b2, att, attbf);
    av_kernel<<<dim3(48, 2), 256, 0, stream>>>(attbf, vt, bmat);
    out_kernel<<<192, 256, 0, stream>>>(bmat, w3t, b3, w4t, b4, yout);
}

// Round 9
// 78.848 us; speedup vs baseline: 4.5801x; 1.0023x over previous
//
#include <hip/hip_runtime.h>
#include <hip/hip_bf16.h>

// N=256, T=12, F=32, T_dim=8, D=64;  c-index: c = kk*768 + t*64 + d  (size 6144)
typedef unsigned short ushort_t;
typedef __bf16 bf16x8 __attribute__((ext_vector_type(8)));
typedef float f32x4 __attribute__((ext_vector_type(4)));
typedef ushort_t ushort8 __attribute__((ext_vector_type(8)));
typedef ushort_t ushort4v __attribute__((ext_vector_type(4)));

#define GLOAD16(gp, lp) \
    __builtin_amdgcn_global_load_lds((const __attribute__((address_space(1))) void*)(gp), \
                                     (__attribute__((address_space(3))) void*)(lp), 16, 0, 0)

__device__ __forceinline__ ushort_t bf16bits(float x) {
    __hip_bfloat16 h = __float2bfloat16(x);
    return *(ushort_t*)&h;
}
__device__ __forceinline__ float bf2f(ushort_t u) {
    unsigned v = (unsigned)u << 16;
    float f;
    __builtin_memcpy(&f, &v, 4);
    return f;
}

// ---------------------------------------------------------------- K1: QKV projection — streaming, one wave per (b, mat)
// lane = (dq = l&15, tg = l>>4); W read as f32x4 (16B/lane); 384 vec-FMA; 8B stores
__global__ __launch_bounds__(256) void qkv_kernel(
    const float* __restrict__ x,
    const float* __restrict__ Wq, const float* __restrict__ Wk, const float* __restrict__ Wv,
    const float* __restrict__ bq, const float* __restrict__ bk, const float* __restrict__ bv,
    ushort_t* __restrict__ qhi, ushort_t* __restrict__ kbf, ushort_t* __restrict__ vbf)
{
    __shared__ float xs[4][12 * 36];       // per-wave x row, t-stride 36 (16B-aligned, bank-spread)
    int tid = threadIdx.x;
    int wid = tid >> 6, l = tid & 63;
    int gid = blockIdx.x * 4 + wid;        // 0..6143, mat-major (consecutive blocks stream one W array)
    int mat = gid >> 11, b = gid & 2047;
    int j = b >> 3;

    const float* W    = (mat == 0) ? Wq : (mat == 1) ? Wk : Wv;
    const float* bias = (mat == 0) ? bq : (mat == 1) ? bk : bv;
    ushort_t*    out  = (mat == 0) ? qhi : (mat == 1) ? kbf : vbf;
    float scale = (mat == 0) ? 0.125f : 1.0f;

    // stage x[j] (384 floats = 96 float4) into padded LDS
    {
        const float4* xsrc = (const float4*)(x + (size_t)j * 384);
        float4 g0 = xsrc[l];
        int flat0 = l * 4;
        float* dst0 = &xs[wid][(flat0 >> 5) * 36 + (flat0 & 31)];
        dst0[0] = g0.x; dst0[1] = g0.y; dst0[2] = g0.z; dst0[3] = g0.w;
        if (l < 32) {
            float4 g1 = xsrc[64 + l];
            int flat1 = 256 + l * 4;
            float* dst1 = &xs[wid][(flat1 >> 5) * 36 + (flat1 & 31)];
            dst1[0] = g1.x; dst1[1] = g1.y; dst1[2] = g1.z; dst1[3] = g1.w;
        }
    }
    __syncthreads();

    int dq = l & 15, tg = l >> 4;          // d-quad 0..15, t-group 0..3 (t = tg*3 + i)
    const f32x4* w4 = (const f32x4*)(W + (size_t)b * 2048);
    f32x4 a0 = {0.f,0.f,0.f,0.f}, a1 = a0, a2 = a0;
    const float* xr = &xs[wid][tg * 3 * 36];
    #pragma unroll
    for (int f4 = 0; f4 < 8; ++f4) {
        f32x4 w0 = w4[(f4 * 4 + 0) * 16 + dq];
        f32x4 w1_ = w4[(f4 * 4 + 1) * 16 + dq];
        f32x4 w2_ = w4[(f4 * 4 + 2) * 16 + dq];
        f32x4 w3_ = w4[(f4 * 4 + 3) * 16 + dq];
        float4 xa = *(const float4*)&xr[0 * 36 + f4 * 4];
        float4 xb = *(const float4*)&xr[1 * 36 + f4 * 4];
        float4 xc = *(const float4*)&xr[2 * 36 + f4 * 4];
        a0 += w0 * xa.x + w1_ * xa.y + w2_ * xa.z + w3_ * xa.w;
        a1 += w0 * xb.x + w1_ * xb.y + w2_ * xb.z + w3_ * xb.w;
        a2 += w0 * xc.x + w1_ * xc.y + w2_ * xc.z + w3_ * xc.w;
    }

    f32x4 bv4 = *(const f32x4*)(bias + (size_t)b * 64 + dq * 4);
    size_t obase = (size_t)b * 768 + dq * 4;
    f32x4 r;
    ushort4v u;
    r = (a0 + bv4) * scale;
    u[0] = bf16bits(r[0]); u[1] = bf16bits(r[1]); u[2] = bf16bits(r[2]); u[3] = bf16bits(r[3]);
    *(ushort4v*)(out + obase + (size_t)(tg * 3 + 0) * 64) = u;
    r = (a1 + bv4) * scale;
    u[0] = bf16bits(r[0]); u[1] = bf16bits(r[1]); u[2] = bf16bits(r[2]); u[3] = bf16bits(r[3]);
    *(ushort4v*)(out + obase + (size_t)(tg * 3 + 1) * 64) = u;
    r = (a2 + bv4) * scale;
    u[0] = bf16bits(r[0]); u[1] = bf16bits(r[1]); u[2] = bf16bits(r[2]); u[3] = bf16bits(r[3]);
    *(ushort4v*)(out + obase + (size_t)(tg * 3 + 2) * 64) = u;
}

// ---------------------------------------------------------------- K2: G build (0..2047) + vt transpose (2048..2431) + w3t (2432..2447) + w4t (2448)
// G[(j*8+m)][kk*768+t*64+d] = sum_s w1[m][kk*144+t*12+s] * k[j*8+kk][s][d]
__global__ __launch_bounds__(256) void gbuild_kernel(
    const ushort_t* __restrict__ kbf, const float* __restrict__ w1,
    const ushort_t* __restrict__ vbf, const float* __restrict__ w3, const float* __restrict__ w4,
    ushort_t* __restrict__ ghi, ushort_t* __restrict__ vt,
    float* __restrict__ w3t, float* __restrict__ w4t)
{
    __shared__ alignas(16) char sbuf[8448];   // union: w1s(4608B)+ks(3072B) | ts(8448B)
    int bx = blockIdx.x, tid = threadIdx.x;

    if (bx < 2048) {
        float* w1s = (float*)sbuf;            // [m][144]
        float* ks  = (float*)sbuf + 1152;     // k row fp32 [t][d]
        int b = bx, j = b >> 3, kk = b & 7;

        #pragma unroll
        for (int r = 0; r < 2; ++r) {
            int c = r * 256 + tid;
            if (c < 288)
                GLOAD16(w1 + (c / 36) * 1152 + kk * 144 + (c % 36) * 4, &w1s[c * 4]);
        }
        if (tid < 96) {
            ushort8 uu = *(const ushort8*)(kbf + (size_t)b * 768 + tid * 8);
            float4 f0, f1;
            f0.x = bf2f(uu[0]); f0.y = bf2f(uu[1]); f0.z = bf2f(uu[2]); f0.w = bf2f(uu[3]);
            f1.x = bf2f(uu[4]); f1.y = bf2f(uu[5]); f1.z = bf2f(uu[6]); f1.w = bf2f(uu[7]);
            ((float4*)ks)[tid * 2]     = f0;
            ((float4*)ks)[tid * 2 + 1] = f1;
        }
        __syncthreads();

        #pragma unroll
        for (int r = 0; r < 3; ++r) {
            int e = r * 256 + tid;               // (m, t, d8)
            int m = e / 96, rem = e - m * 96;
            int t = rem >> 3, d8 = rem & 7;
            const float* w1p = w1s + m * 144 + t * 12;
            float acc[8] = {0.f,0.f,0.f,0.f,0.f,0.f,0.f,0.f};
            #pragma unroll
            for (int s = 0; s < 12; ++s) {
                float wv = w1p[s];
                const float4* kp = (const float4*)(ks + s * 64 + d8 * 8);
                float4 k0 = kp[0], k1 = kp[1];
                acc[0] += wv * k0.x; acc[1] += wv * k0.y;
                acc[2] += wv * k0.z; acc[3] += wv * k0.w;
                acc[4] += wv * k1.x; acc[5] += wv * k1.y;
                acc[6] += wv * k1.z; acc[7] += wv * k1.w;
            }
            ushort8 u;
            #pragma unroll
            for (int dd = 0; dd < 8; ++dd) u[dd] = bf16bits(acc[dd]);
            *(ushort8*)(ghi + ((size_t)j * 8 + m) * 6144 + kk * 768 + t * 64 + d8 * 8) = u;
        }
        return;
    }

    if (bx < 2432) {
        // vbf [j][6144] -> vt[c][j]; 16 c-cols x 256 j per block
        ushort_t (*ts)[264] = (ushort_t(*)[264])sbuf;
        int c0 = (bx - 2048) * 16;
        int cc = tid & 15, jg = tid >> 4;
        #pragma unroll 4
        for (int jj = 0; jj < 16; ++jj) {
            int jx = jg * 16 + jj;
            ts[cc][jx] = vbf[(size_t)jx * 6144 + c0 + cc];
        }
        __syncthreads();
        #pragma unroll
        for (int c = 0; c < 16; ++c)
            vt[(size_t)(c0 + c) * 256 + tid] = ts[c][tid];
        return;
    }
    if (bx < 2448) {
        // w3 (64 dout x 512 c3, c3=d*8+kk) -> w3t[cb*64+dout], cb = kk*64+d
        int wb = bx - 2432;
        #pragma unroll
        for (int r = 0; r < 8; ++r) {
            int e = wb * 2048 + r * 256 + tid;
            int dout = e >> 9, c3 = e & 511;
            int cb = ((c3 & 7) << 6) | (c3 >> 3);
            w3t[cb * 64 + dout] = w3[e];
        }
        return;
    }
    #pragma unroll
    for (int r = 0; r < 8; ++r) {
        int e = r * 256 + tid; int f = e >> 6, dd = e & 63;
        w4t[dd * 32 + f] = w4[e];
    }
}

// ---------------------------------------------------------------- K3: H GEMM
// H[i][(j,m)] = Qhi . G ; block 128x128, 4 waves 64x64, BK=32, nz=16 K-split
// XCD-aware z-major mapping
__global__ __launch_bounds__(256, 2) void hgemm_kernel(
    const ushort_t* __restrict__ qhi, const ushort_t* __restrict__ ghi,
    ushort_t* __restrict__ hpart)
{
    __shared__ ushort_t As[2][128 * 32];
    __shared__ ushort_t Bs[2][128 * 32];

    int tid = threadIdx.x;
    int bid = blockIdx.x;                 // 0..511
    int lane = tid & 63, wid = tid >> 6;
    int wr = wid >> 1, wc = wid & 1;
    int xcd = bid & 7, kq = bid >> 3;     // kq 0..63
    int z = xcd + 8 * (kq >> 5);
    int rem = kq & 31;
    int n0 = (rem & 15) * 128, i0 = (rem >> 4) * 128;
    int kbase = z * 384;
    ushort_t* Hout = hpart + (size_t)z * 524288;

    f32x4 acc[4][4] = {};

    #define STAGE(buf, koff)                                                                 \
    {                                                                                        \
        _Pragma("unroll")                                                                    \
        for (int r = 0; r < 2; ++r) {                                                        \
            int c = r * 256 + tid; int row = c >> 2, slot = c & 3;                           \
            int so = (koff) + ((slot ^ ((row >> 1) & 3)) * 8);                               \
            GLOAD16(qhi + (size_t)(i0 + row) * 6144 + so, &As[buf][c * 8]);                  \
            GLOAD16(ghi + (size_t)(n0 + row) * 6144 + so, &Bs[buf][c * 8]);                  \
        }                                                                                    \
    }

    STAGE(0, kbase);
    int cur = 0;
    for (int s = 0; s < 12; ++s) {
        __syncthreads();
        if (s + 1 < 12) STAGE(cur ^ 1, kbase + (s + 1) * 32);
        bf16x8 a[4], b[4];
        #pragma unroll
        for (int ni = 0; ni < 4; ++ni) {
            int row = wc * 64 + ni * 16 + (lane & 15);
            int slot = (lane >> 4) ^ ((row >> 1) & 3);
            b[ni] = *(const bf16x8*)&Bs[cur][row * 32 + slot * 8];
        }
        #pragma unroll
        for (int mi = 0; mi < 4; ++mi) {
            int row = wr * 64 + mi * 16 + (lane & 15);
            int slot = (lane >> 4) ^ ((row >> 1) & 3);
            a[mi] = *(const bf16x8*)&As[cur][row * 32 + slot * 8];
        }
        #pragma unroll
        for (int mi = 0; mi < 4; ++mi)
            #pragma unroll
            for (int ni = 0; ni < 4; ++ni)
                acc[mi][ni] = __builtin_amdgcn_mfma_f32_16x16x32_bf16(a[mi], b[ni], acc[mi][ni], 0, 0, 0);
        cur ^= 1;
    }
    #undef STAGE

    int r4 = (lane >> 4) * 4, cn = lane & 15;
    #pragma unroll
    for (int mi = 0; mi < 4; ++mi)
        #pragma unroll
        for (int ni = 0; ni < 4; ++ni)
            #pragma unroll
            for (int r = 0; r < 4; ++r) {
                int row = i0 + wr * 64 + mi * 16 + r4 + r;
                int col = n0 + wc * 64 + ni * 16 + cn;
                Hout[(size_t)row * 2048 + col] = bf16bits(acc[mi][ni][r]);
            }
}

// ---------------------------------------------------------------- K4: z-reduce + score + softmax (+ bf16 att)
__global__ __launch_bounds__(256) void score_softmax_kernel(
    const ushort_t* __restrict__ hpart, const float* __restrict__ b1g,
    const float* __restrict__ w2g, const float* __restrict__ b2g,
    float* __restrict__ att, ushort_t* __restrict__ attbf)
{
    int i = blockIdx.x, j = threadIdx.x;
    float hm[8];
    #pragma unroll
    for (int m = 0; m < 8; ++m) hm[m] = b1g[m];
    #pragma unroll 4
    for (int z = 0; z < 16; ++z) {
        ushort8 u = *(const ushort8*)(hpart + (size_t)z * 524288 + (size_t)i * 2048 + j * 8);
        #pragma unroll
        for (int m = 0; m < 8; ++m) hm[m] += bf2f(u[m]);
    }
    float sv = b2g[0];
    #pragma unroll
    for (int m = 0; m < 8; ++m) sv += fmaxf(hm[m], 0.f) * w2g[m];

    __shared__ float wred[4], wred2[4];
    float mx = sv;
    #pragma unroll
    for (int off = 32; off > 0; off >>= 1) mx = fmaxf(mx, __shfl_down(mx, off, 64));
    if ((j & 63) == 0) wred[j >> 6] = mx;
    __syncthreads();
    mx = fmaxf(fmaxf(wred[0], wred[1]), fmaxf(wred[2], wred[3]));

    float e = expf(sv - mx);
    float sum = e;
    #pragma unroll
    for (int off = 32; off > 0; off >>= 1) sum += __shfl_down(sum, off, 64);
    if ((j & 63) == 0) wred2[j >> 6] = sum;
    __syncthreads();
    sum = wred2[0] + wred2[1] + wred2[2] + wred2[3];

    float pv = e / sum;
    att[(size_t)i * 256 + j] = pv;
    attbf[(size_t)i * 256 + j] = bf16bits(pv);
}

// ---------------------------------------------------------------- K5: b = att @ v via MFMA
__global__ __launch_bounds__(256) void av_kernel(
    const ushort_t* __restrict__ attbf, const ushort_t* __restrict__ vt,
    float* __restrict__ bmat)
{
    __shared__ ushort_t As[2][128 * 64];
    __shared__ ushort_t Bs[2][128 * 64];

    int tid = threadIdx.x, lane = tid & 63, wid = tid >> 6;
    int wr = wid >> 1, wc = wid & 1;
    int n0 = blockIdx.x * 128, i0 = blockIdx.y * 128;

    f32x4 acc[4][4] = {};

    #define STAGEAV(buf, koff)                                                              \
    {                                                                                       \
        _Pragma("unroll")                                                                   \
        for (int r = 0; r < 4; ++r) {                                                       \
            int c = r * 256 + tid; int row = c >> 3, slot = c & 7;                          \
            GLOAD16(attbf + (size_t)(i0 + row) * 256 + (koff) + ((slot ^ (row & 7)) * 8),   \
                    &As[buf][c * 8]);                                                       \
        }                                                                                   \
        _Pragma("unroll")                                                                   \
        for (int r = 0; r < 4; ++r) {                                                       \
            int c = r * 256 + tid; int row = c >> 3, slot = c & 7;                          \
            GLOAD16(vt + (size_t)(n0 + row) * 256 + (koff) + ((slot ^ (row & 7)) * 8),      \
                    &Bs[buf][c * 8]);                                                       \
        }                                                                                   \
    }

    int cur = 0;
    STAGEAV(0, 0);
    for (int s = 0; s < 4; ++s) {
        __syncthreads();
        if (s < 3) STAGEAV(cur ^ 1, (s + 1) * 64);
        #pragma unroll
        for (int kh = 0; kh < 2; ++kh) {
            bf16x8 a[4], b[4];
            #pragma unroll
            for (int mi = 0; mi < 4; ++mi) {
                int row = wr * 64 + mi * 16 + (lane & 15);
                int slot = (kh * 4 + (lane >> 4)) ^ (row & 7);
                a[mi] = *(const bf16x8*)&As[cur][row * 64 + slot * 8];
            }
            #pragma unroll
            for (int ni = 0; ni < 4; ++ni) {
                int row = wc * 64 + ni * 16 + (lane & 15);
                int slot = (kh * 4 + (lane >> 4)) ^ (row & 7);
                b[ni] = *(const bf16x8*)&Bs[cur][row * 64 + slot * 8];
            }
            #pragma unroll
            for (int mi = 0; mi < 4; ++mi)
                #pragma unroll
                for (int ni = 0; ni < 4; ++ni)
                    acc[mi][ni] = __builtin_amdgcn_mfma_f32_16x16x32_bf16(a[mi], b[ni], acc[mi][ni], 0, 0, 0);
        }
        cur ^= 1;
    }
    #undef STAGEAV

    int r4 = (lane >> 4) * 4, cn = lane & 15;
    #pragma unroll
    for (int mi = 0; mi < 4; ++mi)
        #pragma unroll
        for (int ni = 0; ni < 4; ++ni) {
            int c = n0 + wc * 64 + ni * 16 + cn;
            int kk = c / 768, rem = c - kk * 768;
            int t = rem >> 6, d = rem & 63;
            #pragma unroll
            for (int r = 0; r < 4; ++r) {
                int row = i0 + wr * 64 + mi * 16 + r4 + r;
                bmat[((size_t)row * 12 + t) * 512 + kk * 64 + d] = acc[mi][ni][r];
            }
        }
}

// ---------------------------------------------------------------- K6: y = relu(b@w3T+b3)@w4T+b4
__global__ __launch_bounds__(256) void out_kernel(
    const float* __restrict__ bmat, const float* __restrict__ w3t, const float* __restrict__ b3,
    const float* __restrict__ w4t, const float* __restrict__ b4, float* __restrict__ yout)
{
    int rb = blockIdx.x * 16;     // rows (i*12+t)
    int tid = threadIdx.x;
    __shared__ float rows[16 * 512];
    __shared__ float y1s[16 * 64];
    const float4* src = (const float4*)(bmat + (size_t)rb * 512);
    #pragma unroll
    for (int r = 0; r < 8; ++r) ((float4*)rows)[tid + r * 256] = src[tid + r * 256];
    __syncthreads();

    int dout = tid & 63, rg = tid >> 6;
    float acc[4];
    float b3v = b3[dout];
    #pragma unroll
    for (int jj = 0; jj < 4; ++jj) acc[jj] = b3v;
    for (int c4 = 0; c4 < 128; ++c4) {
        float w0 = w3t[(c4 * 4 + 0) * 64 + dout];
        float w1v = w3t[(c4 * 4 + 1) * 64 + dout];
        float w2v = w3t[(c4 * 4 + 2) * 64 + dout];
        float w3v = w3t[(c4 * 4 + 3) * 64 + dout];
        #pragma unroll
        for (int jj = 0; jj < 4; ++jj) {
            float4 rv = *(const float4*)&rows[(rg * 4 + jj) * 512 + c4 * 4];
            acc[jj] += rv.x * w0 + rv.y * w1v + rv.z * w2v + rv.w * w3v;
        }
    }
    #pragma unroll
    for (int jj = 0; jj < 4; ++jj) y1s[(rg * 4 + jj) * 64 + dout] = fmaxf(acc[jj], 0.f);
    __syncthreads();

    int f = tid & 31, rh = tid >> 5;
    #pragma unroll
    for (int rr = 0; rr < 2; ++rr) {
        int r = rh * 2 + rr;
        float a2 = b4[f];
        #pragma unroll
        for (int dd = 0; dd < 64; ++dd) a2 += y1s[r * 64 + dd] * w4t[dd * 32 + f];
        yout[(size_t)(rb + r) * 32 + f] = a2;
    }
}

// ---------------------------------------------------------------- launch
extern "C" void kernel_launch(void* const* d_in, const int* in_sizes, int n_in,
                              void* d_out, int out_size, void* d_ws, size_t ws_size,
                              hipStream_t stream) {
    (void)in_sizes; (void)n_in; (void)out_size; (void)ws_size;
    const float* x  = (const float*)d_in[0];
    const float* Wq = (const float*)d_in[1];
    const float* Wk = (const float*)d_in[2];
    const float* Wv = (const float*)d_in[3];
    const float* bq = (const float*)d_in[4];
    const float* bk = (const float*)d_in[5];
    const float* bv = (const float*)d_in[6];
    const float* w1 = (const float*)d_in[7];
    const float* b1 = (const float*)d_in[8];
    const float* w2 = (const float*)d_in[9];
    const float* b2 = (const float*)d_in[10];
    const float* w3 = (const float*)d_in[11];
    const float* b3 = (const float*)d_in[12];
    const float* w4 = (const float*)d_in[13];
    const float* b4 = (const float*)d_in[14];

    float* ws = (float*)d_ws;
    // layout (float-slot offsets)
    ushort_t* hpart = (ushort_t*)ws;                     // 16z x 524288 ushorts = [0, 4194304)
    size_t    off   = 4194304;
    ushort_t* qhi   = (ushort_t*)(ws + off);             // 1,572,864 ushorts
    ushort_t* ghi   = (ushort_t*)(ws + off + 786432);    // 12,582,912 ushorts
    ushort_t* vbf   = (ushort_t*)(ws + off + 7077888);   // 1,572,864 ushorts
    ushort_t* vt    = (ushort_t*)(ws + off + 7864320);   // 1,572,864 ushorts
    ushort_t* attbf = (ushort_t*)(ws + off + 8650752);   // 65,536 ushorts
    float*    w3t   = ws + off + 8683520;                // 32,768
    float*    w4t   = ws + off + 8716288;                // 2,048
    ushort_t* kbf   = (ushort_t*)(ws + off + 8718336);   // 1,572,864 ushorts
    float*    bmat  = (float*)ghi;                       // reuse (ghi dead after hgemm)

    float* yout = (float*)d_out;              // 98304
    float* att  = (float*)d_out + 98304;      // 65536

    qkv_kernel<<<1536, 256, 0, stream>>>(x, Wq, Wk, Wv, bq, bk, bv, qhi, kbf, vbf);
    gbuild_kernel<<<2449, 256, 0, stream>>>(kbf, w1, vbf, w3, w4, ghi, vt, w3t, w4t);
    hgemm_kernel<<<512, 256, 0, stream>>>(qhi, ghi, hpart);
    score_softmax_kernel<<<256, 256, 0, stream>>>(hpart, b1, w2, b2, att, attbf);
    av_kernel<<<dim3(48, 2), 256, 0, stream>>>(attbf, vt, bmat);
    out_kernel<<<192, 256, 0, stream>>>(bmat, w3t, b3, w4t, b4, yout);
}